// Round 1
// baseline (330.288 us; speedup 1.0000x reference)
//
#include <hip/hip_runtime.h>

typedef unsigned short u16;
typedef short short8 __attribute__((ext_vector_type(8)));
typedef float f32x4 __attribute__((ext_vector_type(4)));
typedef float float4v __attribute__((ext_vector_type(4)));
typedef u16 u16x4 __attribute__((ext_vector_type(4)));

// ---------- helpers ----------
__device__ __forceinline__ u16 f2bf(float f) {
  union { float f; unsigned u; } v; v.f = f;
  unsigned r = v.u + 0x7FFFu + ((v.u >> 16) & 1u);   // round-to-nearest-even
  return (u16)(r >> 16);
}

__device__ __forceinline__ void gload16(const u16* g, u16* l) {
  __builtin_amdgcn_global_load_lds(
      (const __attribute__((address_space(1))) void*)g,
      (__attribute__((address_space(3))) void*)l, 16, 0, 0);
}

// ---------- mask format detection ----------
// fmt: 0 = u8/bool, 1 = i32, 2 = f32, 3 = i64
__global__ void detect_kernel(const unsigned char* __restrict__ m, int* __restrict__ flag) {
  __shared__ int f3F, fOdd, fOddD;
  if (threadIdx.x == 0) { f3F = 0; fOdd = 0; fOddD = 0; }
  __syncthreads();
  int a = 0, b = 0, c = 0;
  for (int i = threadIdx.x; i < 16384; i += 256) {
    unsigned char v = m[i];
    if (v == 0x3F) a = 1;            // f32 1.0f high byte
    if (v && (i & 3)) b = 1;         // nonzero off a dword boundary -> bytes
    if (v && ((i >> 2) & 1)) c = 1;  // nonzero in odd dword -> i32 (not i64)
  }
  if (a) atomicOr(&f3F, 1);
  if (b) atomicOr(&fOdd, 1);
  if (c) atomicOr(&fOddD, 1);
  __syncthreads();
  if (threadIdx.x == 0)
    *flag = f3F ? 2 : (fOdd ? 0 : (fOddD ? 1 : 3));
}

// ---------- x: f32 -> bf16, straight copy ----------
__global__ __launch_bounds__(256) void xcvt_kernel(const float* __restrict__ x, u16* __restrict__ xb) {
  int i = (blockIdx.x * 256 + threadIdx.x) * 4;
  float4v v = *(const float4v*)(x + i);
  u16x4 o;
  o[0] = f2bf(v[0]); o[1] = f2bf(v[1]); o[2] = f2bf(v[2]); o[3] = f2bf(v[3]);
  *(u16x4*)(xb + i) = o;
}

// ---------- W: f32 [K][N] -> bf16 transposed [N][K] (4 weights via blockIdx.z) ----------
__global__ __launch_bounds__(256) void wcvt_kernel(
    const float* __restrict__ W0, const float* __restrict__ W1,
    const float* __restrict__ W2, const float* __restrict__ W3,
    u16* __restrict__ Wt) {
  __shared__ float t[32][33];
  int z = blockIdx.z;
  const float* W = (z == 0) ? W0 : (z == 1) ? W1 : (z == 2) ? W2 : W3;
  u16* out = Wt + (size_t)z * 1024 * 1024;
  int n0 = blockIdx.x * 32, k0 = blockIdx.y * 32;
  int tx = threadIdx.x & 31, ty = threadIdx.x >> 5;
#pragma unroll
  for (int j = 0; j < 4; ++j)
    t[ty + 8 * j][tx] = W[(size_t)(k0 + ty + 8 * j) * 1024 + n0 + tx];
  __syncthreads();
#pragma unroll
  for (int j = 0; j < 4; ++j)
    out[(size_t)(n0 + ty + 8 * j) * 1024 + k0 + tx] = f2bf(t[tx][ty + 8 * j]);
}

// ---------- 128x128 bf16 GEMM, A[M][K] x Bt[N][K]^T + bias ----------
// phase 0: z in {0,1,2} -> q-layout / k-layout / vT-layout bf16 epilogues
// phase 1: f32 output straight to d_out
__global__ __launch_bounds__(256)
void gemm128_kernel(const u16* __restrict__ A,
                    const u16* __restrict__ BtQ, const u16* __restrict__ BtK, const u16* __restrict__ BtV,
                    const float* __restrict__ bQ, const float* __restrict__ bK, const float* __restrict__ bV,
                    u16* __restrict__ qb, u16* __restrict__ kb, u16* __restrict__ vT,
                    float* __restrict__ fo, int phase) {
  constexpr int K = 1024;
  __shared__ u16 As[128 * 32];
  __shared__ u16 Bs[128 * 32];
  const int tid = threadIdx.x;
  const int lane = tid & 63, w = tid >> 6;
  const int l15 = lane & 15, l4 = lane >> 4;
  const int m0 = blockIdx.x * 128, n0 = blockIdx.y * 128;
  const int z = blockIdx.z;
  const u16* Bt = (z == 0) ? BtQ : (z == 1) ? BtK : BtV;
  const float* bias = (z == 0) ? bQ : (z == 1) ? bK : bV;
  const int wr = w >> 1, wc = w & 1;

  f32x4 acc[4][4] = {};

  const int c0 = tid, c1 = 256 + tid;
  const u16* ga0 = A + (size_t)(m0 + (c0 >> 2)) * K + (c0 & 3) * 8;
  const u16* ga1 = A + (size_t)(m0 + (c1 >> 2)) * K + (c1 & 3) * 8;
  const u16* gb0 = Bt + (size_t)(n0 + (c0 >> 2)) * K + (c0 & 3) * 8;
  const u16* gb1 = Bt + (size_t)(n0 + (c1 >> 2)) * K + (c1 & 3) * 8;
  u16* la0 = As + c0 * 8;
  u16* la1 = As + c1 * 8;
  u16* lb0 = Bs + c0 * 8;
  u16* lb1 = Bs + c1 * 8;

  for (int kt = 0; kt < K; kt += 32) {
    gload16(ga0 + kt, la0);
    gload16(ga1 + kt, la1);
    gload16(gb0 + kt, lb0);
    gload16(gb1 + kt, lb1);
    __syncthreads();   // compiler emits vmcnt(0) drain before barrier
    short8 af[4], bfr[4];
#pragma unroll
    for (int r = 0; r < 4; ++r)
      af[r] = *(const short8*)(As + (wr * 64 + r * 16 + l15) * 32 + l4 * 8);
#pragma unroll
    for (int c = 0; c < 4; ++c)
      bfr[c] = *(const short8*)(Bs + (wc * 64 + c * 16 + l15) * 32 + l4 * 8);
#pragma unroll
    for (int r = 0; r < 4; ++r)
#pragma unroll
      for (int c = 0; c < 4; ++c)
        acc[r][c] = __builtin_amdgcn_mfma_f32_16x16x32_bf16(af[r], bfr[c], acc[r][c], 0, 0, 0);
    __syncthreads();
  }

  float bv4[4];
#pragma unroll
  for (int c = 0; c < 4; ++c) bv4[c] = bias[n0 + wc * 64 + c * 16 + l15];

#pragma unroll
  for (int r = 0; r < 4; ++r) {
#pragma unroll
    for (int c = 0; c < 4; ++c) {
#pragma unroll
      for (int j = 0; j < 4; ++j) {
        float val = acc[r][c][j] + bv4[c];
        int row = m0 + wr * 64 + r * 16 + l4 * 4 + j;  // m index (= b*1024+s)
        int col = n0 + wc * 64 + c * 16 + l15;         // n index (= h*64+d)
        if (phase == 0) {
          int b = row >> 10, s = row & 1023, hh = col >> 6, d = col & 63;
          if (z < 2) {
            u16* dst = (z == 0) ? qb : kb;
            dst[(((size_t)b * 16 + hh) * 1024 + s) * 64 + d] = f2bf(val);
          } else {
            vT[(((size_t)b * 16 + hh) * 64 + d) * 1024 + s] = f2bf(val);
          }
        } else {
          fo[(size_t)row * 1024 + col] = val;
        }
      }
    }
  }
}

// ---------- flash attention: per-wave 16 q-rows, KBLK=64, online softmax ----------
__global__ __launch_bounds__(256)
void attn_kernel(const u16* __restrict__ qb, const u16* __restrict__ kb, const u16* __restrict__ vT,
                 const void* __restrict__ maskp, const float* __restrict__ temp,
                 const int* __restrict__ fmtp, u16* __restrict__ oh) {
  __shared__ u16 P[4][16 * 64];
  const int tid = threadIdx.x, lane = tid & 63, w = tid >> 6;
  const int l15 = lane & 15, l4 = lane >> 4;
  const int bh = blockIdx.y, b = bh >> 4, h = bh & 15;
  const int q0 = blockIdx.x * 64 + w * 16;  // this wave's q base within S
  const u16* qp = qb + ((size_t)bh * 1024 + q0) * 64;
  const u16* kp = kb + (size_t)bh * 1024 * 64;
  const u16* vp = vT + (size_t)bh * 64 * 1024;
  const float sc2 = temp[h] * 0.125f * 1.4426950408889634f;  // /sqrt(64)*temp, log2-domain
  const int fmt = *fmtp;
  u16* Pw = &P[w][0];

  short8 qf0 = *(const short8*)(qp + (size_t)l15 * 64 + l4 * 8);
  short8 qf1 = *(const short8*)(qp + (size_t)l15 * 64 + 32 + l4 * 8);

  float mrow[4] = {-1e30f, -1e30f, -1e30f, -1e30f};
  float lrow[4] = {0.f, 0.f, 0.f, 0.f};
  f32x4 oacc[4] = {};

  const size_t mrowbase = ((size_t)bh * 1024 + (q0 + l4 * 4)) * 1024 + l15;

  for (int k0 = 0; k0 < 1024; k0 += 64) {
    // ---- S = Q K^T (16x64 per wave) ----
    f32x4 s[4] = {};
#pragma unroll
    for (int cb = 0; cb < 4; ++cb) {
      const u16* kr = kp + (size_t)(k0 + cb * 16 + l15) * 64 + l4 * 8;
      short8 kf0 = *(const short8*)kr;
      short8 kf1 = *(const short8*)(kr + 32);
      s[cb] = __builtin_amdgcn_mfma_f32_16x16x32_bf16(qf0, kf0, s[cb], 0, 0, 0);
      s[cb] = __builtin_amdgcn_mfma_f32_16x16x32_bf16(qf1, kf1, s[cb], 0, 0, 0);
    }
    // ---- mask bits (format-dispatched, uniform branch) ----
    unsigned kbits = 0;
    if (fmt == 0) {
      const unsigned char* mp = (const unsigned char*)maskp;
#pragma unroll
      for (int j = 0; j < 4; ++j)
#pragma unroll
        for (int cb = 0; cb < 4; ++cb)
          if (mp[mrowbase + (size_t)j * 1024 + k0 + cb * 16]) kbits |= 1u << (j * 4 + cb);
    } else if (fmt == 1) {
      const int* mp = (const int*)maskp;
#pragma unroll
      for (int j = 0; j < 4; ++j)
#pragma unroll
        for (int cb = 0; cb < 4; ++cb)
          if (mp[mrowbase + (size_t)j * 1024 + k0 + cb * 16]) kbits |= 1u << (j * 4 + cb);
    } else if (fmt == 2) {
      const float* mp = (const float*)maskp;
#pragma unroll
      for (int j = 0; j < 4; ++j)
#pragma unroll
        for (int cb = 0; cb < 4; ++cb)
          if (mp[mrowbase + (size_t)j * 1024 + k0 + cb * 16] != 0.f) kbits |= 1u << (j * 4 + cb);
    } else {
      const long long* mp = (const long long*)maskp;
#pragma unroll
      for (int j = 0; j < 4; ++j)
#pragma unroll
        for (int cb = 0; cb < 4; ++cb)
          if (mp[mrowbase + (size_t)j * 1024 + k0 + cb * 16] != 0) kbits |= 1u << (j * 4 + cb);
    }
    // ---- online softmax (log2 domain), P -> LDS (XOR-swizzled) ----
#pragma unroll
    for (int j = 0; j < 4; ++j) {
      float sv[4];
#pragma unroll
      for (int cb = 0; cb < 4; ++cb)
        sv[cb] = ((kbits >> (j * 4 + cb)) & 1) ? s[cb][j] * sc2 : -1e30f;
      float mt = fmaxf(fmaxf(sv[0], sv[1]), fmaxf(sv[2], sv[3]));
#pragma unroll
      for (int o = 1; o < 16; o <<= 1) mt = fmaxf(mt, __shfl_xor(mt, o));
      float mnew = fmaxf(mrow[j], mt);
      float al = exp2f(mrow[j] - mnew);
      float p0 = exp2f(sv[0] - mnew), p1 = exp2f(sv[1] - mnew);
      float p2 = exp2f(sv[2] - mnew), p3 = exp2f(sv[3] - mnew);
      float rs = (p0 + p1) + (p2 + p3);
#pragma unroll
      for (int o = 1; o < 16; o <<= 1) rs += __shfl_xor(rs, o);
      lrow[j] = lrow[j] * al + rs;
      mrow[j] = mnew;
#pragma unroll
      for (int dcb = 0; dcb < 4; ++dcb) oacc[dcb][j] *= al;
      int prow = l4 * 4 + j;
      int sw = (prow & 7) << 3;
      Pw[prow * 64 + ((0 * 16 + l15) ^ sw)] = f2bf(p0);
      Pw[prow * 64 + ((1 * 16 + l15) ^ sw)] = f2bf(p1);
      Pw[prow * 64 + ((2 * 16 + l15) ^ sw)] = f2bf(p2);
      Pw[prow * 64 + ((3 * 16 + l15) ^ sw)] = f2bf(p3);
    }
    asm volatile("s_waitcnt lgkmcnt(0)" ::: "memory");
    __builtin_amdgcn_sched_barrier(0);
    // ---- O += P V ----
#pragma unroll
    for (int ks = 0; ks < 2; ++ks) {
      short8 pa = *(const short8*)(Pw + l15 * 64 + ((ks * 32 + l4 * 8) ^ ((l15 & 7) << 3)));
#pragma unroll
      for (int dcb = 0; dcb < 4; ++dcb) {
        short8 vf = *(const short8*)(vp + (size_t)(dcb * 16 + l15) * 1024 + k0 + ks * 32 + l4 * 8);
        oacc[dcb] = __builtin_amdgcn_mfma_f32_16x16x32_bf16(pa, vf, oacc[dcb], 0, 0, 0);
      }
    }
  }
  // ---- finalize: O/l -> oh[b, s, h*64+d] (bf16) ----
#pragma unroll
  for (int dcb = 0; dcb < 4; ++dcb)
#pragma unroll
    for (int j = 0; j < 4; ++j) {
      float ov = oacc[dcb][j] / lrow[j];
      int srow = q0 + l4 * 4 + j;
      oh[((size_t)b * 1024 + srow) * 1024 + h * 64 + dcb * 16 + l15] = f2bf(ov);
    }
}

// ---------- launch ----------
extern "C" void kernel_launch(void* const* d_in, const int* in_sizes, int n_in,
                              void* d_out, int out_size, void* d_ws, size_t ws_size,
                              hipStream_t stream) {
  const float* x = (const float*)d_in[0];
  const float* Wq = (const float*)d_in[1];
  const float* bq = (const float*)d_in[2];
  const float* Wk = (const float*)d_in[3];
  const float* bk = (const float*)d_in[4];
  const float* Wv = (const float*)d_in[5];
  const float* bv = (const float*)d_in[6];
  const float* Wo = (const float*)d_in[7];
  const float* bo = (const float*)d_in[8];
  const float* temp = (const float*)d_in[9];
  const void* mask = (const void*)d_in[10];

  char* ws = (char*)d_ws;
  int* flag = (int*)ws;
  u16* xb = (u16*)(ws + 256);                 // 8 MiB  (x bf16; reused as oh later)
  u16* Wt = xb + (size_t)4 * 1024 * 1024;     // 8 MiB  (Wq^T,Wk^T,Wv^T,Wo^T bf16)
  u16* qbuf = Wt + (size_t)4 * 1024 * 1024;   // 8 MiB  [B,H,S,D]
  u16* kbuf = qbuf + (size_t)4 * 1024 * 1024; // 8 MiB  [B,H,S,D]
  u16* vTb = kbuf + (size_t)4 * 1024 * 1024;  // 8 MiB  [B,H,D,S]
  u16* oh = xb;                               // alias: xb dead after QKV GEMM

  detect_kernel<<<1, 256, 0, stream>>>((const unsigned char*)mask, flag);
  xcvt_kernel<<<4096, 256, 0, stream>>>(x, xb);
  wcvt_kernel<<<dim3(32, 32, 4), 256, 0, stream>>>(Wq, Wk, Wv, Wo, Wt);
  gemm128_kernel<<<dim3(32, 8, 3), 256, 0, stream>>>(
      xb, Wt, Wt + 1024 * 1024, Wt + 2 * 1024 * 1024,
      bq, bk, bv, qbuf, kbuf, vTb, nullptr, 0);
  attn_kernel<<<dim3(16, 64), 256, 0, stream>>>(qbuf, kbuf, vTb, mask, temp, flag, oh);
  gemm128_kernel<<<dim3(32, 8, 1), 256, 0, stream>>>(
      oh, Wt + 3 * 1024 * 1024, nullptr, nullptr,
      bo, nullptr, nullptr, nullptr, nullptr, nullptr, (float*)d_out, 1);
}

// Round 2
// 311.400 us; speedup vs baseline: 1.0607x; 1.0607x over previous
//
#include <hip/hip_runtime.h>

typedef unsigned short u16;
typedef short short8 __attribute__((ext_vector_type(8)));
typedef float f32x4 __attribute__((ext_vector_type(4)));
typedef float float4v __attribute__((ext_vector_type(4)));
typedef u16 u16x4 __attribute__((ext_vector_type(4)));
typedef unsigned long long u64;

// ---------- helpers ----------
__device__ __forceinline__ u16 f2bf(float f) {
  union { float f; unsigned u; } v; v.f = f;
  unsigned r = v.u + 0x7FFFu + ((v.u >> 16) & 1u);   // round-to-nearest-even
  return (u16)(r >> 16);
}

__device__ __forceinline__ unsigned cvtpk(float lo, float hi) {
  unsigned r;
  asm("v_cvt_pk_bf16_f32 %0, %1, %2" : "=v"(r) : "v"(lo), "v"(hi));
  return r;
}

__device__ __forceinline__ void gload16(const u16* g, u16* l) {
  __builtin_amdgcn_global_load_lds(
      (const __attribute__((address_space(1))) void*)g,
      (__attribute__((address_space(3))) void*)l, 16, 0, 0);
}

// ---------- mask format detection ----------
// fmt: 0 = u8/bool, 1 = i32, 2 = f32, 3 = i64
__global__ void detect_kernel(const unsigned char* __restrict__ m, int* __restrict__ flag) {
  __shared__ int f3F, fOdd, fOddD;
  if (threadIdx.x == 0) { f3F = 0; fOdd = 0; fOddD = 0; }
  __syncthreads();
  int a = 0, b = 0, c = 0;
  for (int i = threadIdx.x; i < 16384; i += 256) {
    unsigned char v = m[i];
    if (v == 0x3F) a = 1;            // f32 1.0f high byte
    if (v && (i & 3)) b = 1;         // nonzero off a dword boundary -> bytes
    if (v && ((i >> 2) & 1)) c = 1;  // nonzero in odd dword -> i32 (not i64)
  }
  if (a) atomicOr(&f3F, 1);
  if (b) atomicOr(&fOdd, 1);
  if (c) atomicOr(&fOddD, 1);
  __syncthreads();
  if (threadIdx.x == 0)
    *flag = f3F ? 2 : (fOdd ? 0 : (fOddD ? 1 : 3));
}

// ---------- mask -> bitmask, k-tile-major: word[(bh*16 + kt)*1024 + q] ----------
// bit j of word = mask[bh, q, kt*64 + j] != 0
__global__ __launch_bounds__(256)
void maskbits_kernel(const void* __restrict__ mask, const int* __restrict__ fmtp,
                     u64* __restrict__ bits) {
  const int fmt = *fmtp;
  constexpr int NW = 1024 * 1024;  // total words (64M elements / 64)
  if (fmt == 0) {
    // byte mask: each thread builds one word from 64 consecutive bytes (4x16B loads)
    const uint4* mp = (const uint4*)mask;
    for (int wi = blockIdx.x * 256 + threadIdx.x; wi < NW; wi += gridDim.x * 256) {
      u64 b = 0;
#pragma unroll
      for (int i = 0; i < 4; ++i) {
        uint4 v = mp[(size_t)wi * 4 + i];
        unsigned x[4] = {v.x, v.y, v.z, v.w};
#pragma unroll
        for (int d = 0; d < 4; ++d) {
#pragma unroll
          for (int by = 0; by < 4; ++by)
            if (x[d] & (0xFFu << (by * 8))) b |= 1ULL << (i * 16 + d * 4 + by);
        }
      }
      int bh = wi >> 14, q = (wi >> 4) & 1023, kt = wi & 15;
      bits[((size_t)bh * 16 + kt) * 1024 + q] = b;
    }
  } else {
    // wide element types: one element per lane, ballot builds the word
    const int gw = (blockIdx.x * 256 + threadIdx.x) >> 6;
    const int lane = threadIdx.x & 63;
    const int nwaves = gridDim.x * 4;
    for (int wi = gw; wi < NW; wi += nwaves) {
      size_t e = (size_t)wi * 64 + lane;
      bool v;
      if (fmt == 1)      v = ((const int*)mask)[e] != 0;
      else if (fmt == 2) v = ((const float*)mask)[e] != 0.f;
      else               v = ((const long long*)mask)[e] != 0;
      u64 b = __ballot(v);
      if (lane == 0) {
        int bh = wi >> 14, q = (wi >> 4) & 1023, kt = wi & 15;
        bits[((size_t)bh * 16 + kt) * 1024 + q] = b;
      }
    }
  }
}

// ---------- x: f32 -> bf16, straight copy ----------
__global__ __launch_bounds__(256) void xcvt_kernel(const float* __restrict__ x, u16* __restrict__ xb) {
  int i = (blockIdx.x * 256 + threadIdx.x) * 4;
  float4v v = *(const float4v*)(x + i);
  u16x4 o;
  o[0] = f2bf(v[0]); o[1] = f2bf(v[1]); o[2] = f2bf(v[2]); o[3] = f2bf(v[3]);
  *(u16x4*)(xb + i) = o;
}

// ---------- W: f32 [K][N] -> bf16 transposed [N][K] (4 weights via blockIdx.z) ----------
__global__ __launch_bounds__(256) void wcvt_kernel(
    const float* __restrict__ W0, const float* __restrict__ W1,
    const float* __restrict__ W2, const float* __restrict__ W3,
    u16* __restrict__ Wt) {
  __shared__ float t[32][33];
  int z = blockIdx.z;
  const float* W = (z == 0) ? W0 : (z == 1) ? W1 : (z == 2) ? W2 : W3;
  u16* out = Wt + (size_t)z * 1024 * 1024;
  int n0 = blockIdx.x * 32, k0 = blockIdx.y * 32;
  int tx = threadIdx.x & 31, ty = threadIdx.x >> 5;
#pragma unroll
  for (int j = 0; j < 4; ++j)
    t[ty + 8 * j][tx] = W[(size_t)(k0 + ty + 8 * j) * 1024 + n0 + tx];
  __syncthreads();
#pragma unroll
  for (int j = 0; j < 4; ++j)
    out[(size_t)(n0 + ty + 8 * j) * 1024 + k0 + tx] = f2bf(t[tx][ty + 8 * j]);
}

// ---------- 128x128 bf16 GEMM, A[M][K] x Bt[N][K]^T + bias ----------
__global__ __launch_bounds__(256)
void gemm128_kernel(const u16* __restrict__ A,
                    const u16* __restrict__ BtQ, const u16* __restrict__ BtK, const u16* __restrict__ BtV,
                    const float* __restrict__ bQ, const float* __restrict__ bK, const float* __restrict__ bV,
                    u16* __restrict__ qb, u16* __restrict__ kb, u16* __restrict__ vT,
                    float* __restrict__ fo, int phase) {
  constexpr int K = 1024;
  __shared__ u16 As[128 * 32];
  __shared__ u16 Bs[128 * 32];
  const int tid = threadIdx.x;
  const int lane = tid & 63, w = tid >> 6;
  const int l15 = lane & 15, l4 = lane >> 4;
  const int m0 = blockIdx.x * 128, n0 = blockIdx.y * 128;
  const int z = blockIdx.z;
  const u16* Bt = (z == 0) ? BtQ : (z == 1) ? BtK : BtV;
  const float* bias = (z == 0) ? bQ : (z == 1) ? bK : bV;
  const int wr = w >> 1, wc = w & 1;

  f32x4 acc[4][4] = {};

  const int c0 = tid, c1 = 256 + tid;
  const u16* ga0 = A + (size_t)(m0 + (c0 >> 2)) * K + (c0 & 3) * 8;
  const u16* ga1 = A + (size_t)(m0 + (c1 >> 2)) * K + (c1 & 3) * 8;
  const u16* gb0 = Bt + (size_t)(n0 + (c0 >> 2)) * K + (c0 & 3) * 8;
  const u16* gb1 = Bt + (size_t)(n0 + (c1 >> 2)) * K + (c1 & 3) * 8;
  u16* la0 = As + c0 * 8;
  u16* la1 = As + c1 * 8;
  u16* lb0 = Bs + c0 * 8;
  u16* lb1 = Bs + c1 * 8;

  for (int kt = 0; kt < K; kt += 32) {
    gload16(ga0 + kt, la0);
    gload16(ga1 + kt, la1);
    gload16(gb0 + kt, lb0);
    gload16(gb1 + kt, lb1);
    __syncthreads();
    short8 af[4], bfr[4];
#pragma unroll
    for (int r = 0; r < 4; ++r)
      af[r] = *(const short8*)(As + (wr * 64 + r * 16 + l15) * 32 + l4 * 8);
#pragma unroll
    for (int c = 0; c < 4; ++c)
      bfr[c] = *(const short8*)(Bs + (wc * 64 + c * 16 + l15) * 32 + l4 * 8);
#pragma unroll
    for (int r = 0; r < 4; ++r)
#pragma unroll
      for (int c = 0; c < 4; ++c)
        acc[r][c] = __builtin_amdgcn_mfma_f32_16x16x32_bf16(af[r], bfr[c], acc[r][c], 0, 0, 0);
    __syncthreads();
  }

  float bv4[4];
#pragma unroll
  for (int c = 0; c < 4; ++c) bv4[c] = bias[n0 + wc * 64 + c * 16 + l15];

#pragma unroll
  for (int r = 0; r < 4; ++r) {
#pragma unroll
    for (int c = 0; c < 4; ++c) {
#pragma unroll
      for (int j = 0; j < 4; ++j) {
        float val = acc[r][c][j] + bv4[c];
        int row = m0 + wr * 64 + r * 16 + l4 * 4 + j;  // m index (= b*1024+s)
        int col = n0 + wc * 64 + c * 16 + l15;         // n index (= h*64+d)
        if (phase == 0) {
          int b = row >> 10, s = row & 1023, hh = col >> 6, d = col & 63;
          if (z < 2) {
            u16* dst = (z == 0) ? qb : kb;
            dst[(((size_t)b * 16 + hh) * 1024 + s) * 64 + d] = f2bf(val);
          } else {
            vT[(((size_t)b * 16 + hh) * 64 + d) * 1024 + s] = f2bf(val);
          }
        } else {
          fo[(size_t)row * 1024 + col] = val;
        }
      }
    }
  }
}

// ---------- flash attention, swapped QK^T (S^T in regs, lane-local softmax) ----------
// wave handles 16 q-rows; S^T = mfma(K,Q): lane holds col q=l15, rows k=cb*16+l4*4+j
// PV computed as O^T = V^T * P^T so alpha/1:l rescales are lane-local.
__global__ __launch_bounds__(256)
void attn_kernel(const u16* __restrict__ qb, const u16* __restrict__ kb, const u16* __restrict__ vT,
                 const u64* __restrict__ mbits, const float* __restrict__ temp,
                 u16* __restrict__ oh) {
  __shared__ u16 P[4][16 * 64];  // per-wave 16q x 64k bf16, XOR-swizzled rows
  const int tid = threadIdx.x, lane = tid & 63, w = tid >> 6;
  const int l15 = lane & 15, l4 = lane >> 4;
  const int bh = blockIdx.y, b = bh >> 4, h = bh & 15;
  const int q0 = blockIdx.x * 64 + w * 16;
  const u16* qp = qb + ((size_t)bh * 1024 + q0) * 64;
  const u16* kp = kb + (size_t)bh * 1024 * 64;
  const u16* vp = vT + (size_t)bh * 64 * 1024;
  const float sc2 = temp[h] * 0.125f * 1.4426950408889634f;  // temp/sqrt(64)*log2(e)
  char* Pw = (char*)&P[w][0];
  const int swz = (l15 & 7) << 4;
  char* Prow = Pw + l15 * 128;

  // Q as B-fragment: col = q = l15, k-slice = l4*8
  short8 qf0 = *(const short8*)(qp + (size_t)l15 * 64 + l4 * 8);
  short8 qf1 = *(const short8*)(qp + (size_t)l15 * 64 + 32 + l4 * 8);

  const u16* vb[4];
#pragma unroll
  for (int db = 0; db < 4; ++db) vb[db] = vp + (size_t)(db * 16 + l15) * 1024;

  float m = -1e30f, l = 0.f;
  f32x4 oacc[4] = {};  // O^T: row d = db*16 + l4*4 + j, col q = l15

  // bitmask: word[(bh*16 + kt)*1024 + q] — wave reads 16 consecutive words/tile
  const u64* mb = mbits + (size_t)bh * 16 * 1024 + q0 + l15;
  u64 wcur = mb[0];

  for (int t = 0; t < 16; ++t) {
    const int k0 = t * 64;
    u64 wnext = (t < 15) ? mb[(t + 1) * 1024] : 0ULL;

    // ---- S^T = K Q^T : A = K-frag (row k=cb*16+l15), B = Q-frag ----
    f32x4 s[4] = {};
    __builtin_amdgcn_s_setprio(1);
#pragma unroll
    for (int cb = 0; cb < 4; ++cb) {
      const u16* kr = kp + (size_t)(k0 + cb * 16 + l15) * 64 + l4 * 8;
      short8 kf0 = *(const short8*)kr;
      short8 kf1 = *(const short8*)(kr + 32);
      s[cb] = __builtin_amdgcn_mfma_f32_16x16x32_bf16(kf0, qf0, s[cb], 0, 0, 0);
      s[cb] = __builtin_amdgcn_mfma_f32_16x16x32_bf16(kf1, qf1, s[cb], 0, 0, 0);
    }
    __builtin_amdgcn_s_setprio(0);

    // ---- mask + lane-local online softmax (all 16 scores belong to q=l15) ----
    float xx[4][4];
#pragma unroll
    for (int cb = 0; cb < 4; ++cb) {
      unsigned nib = (unsigned)(wcur >> (cb * 16 + l4 * 4)) & 15u;
#pragma unroll
      for (int j = 0; j < 4; ++j)
        xx[cb][j] = ((nib >> j) & 1) ? s[cb][j] * sc2 : -1e30f;
    }
    float mt = xx[0][0];
#pragma unroll
    for (int cb = 0; cb < 4; ++cb)
#pragma unroll
      for (int j = 0; j < 4; ++j) mt = fmaxf(mt, xx[cb][j]);
    mt = fmaxf(mt, __shfl_xor(mt, 16));
    mt = fmaxf(mt, __shfl_xor(mt, 32));
    float mnew = fmaxf(m, mt);
    float al = exp2f(m - mnew);
    float rs = 0.f;
#pragma unroll
    for (int cb = 0; cb < 4; ++cb)
#pragma unroll
      for (int j = 0; j < 4; ++j) {
        xx[cb][j] = exp2f(xx[cb][j] - mnew);
        rs += xx[cb][j];
      }
    rs += __shfl_xor(rs, 16);
    rs += __shfl_xor(rs, 32);
    l = l * al + rs;
    m = mnew;
#pragma unroll
    for (int db = 0; db < 4; ++db) oacc[db] *= al;

    // ---- P -> LDS, row q=l15 (128B), byte bits 4-6 XOR-swizzled ----
#pragma unroll
    for (int cb = 0; cb < 4; ++cb) {
      unsigned w0 = cvtpk(xx[cb][0], xx[cb][1]);
      unsigned w1 = cvtpk(xx[cb][2], xx[cb][3]);
      unsigned o2[2] = {w0, w1};
      *(unsigned long long*)(Prow + ((cb * 32 + l4 * 8) ^ swz)) = *(unsigned long long*)o2;
    }
    asm volatile("s_waitcnt lgkmcnt(0)" ::: "memory");
    __builtin_amdgcn_sched_barrier(0);

    // ---- O^T += V^T P^T : A = V^T-frag (row d=db*16+l15), B = P^T from LDS ----
    __builtin_amdgcn_s_setprio(1);
#pragma unroll
    for (int ks = 0; ks < 2; ++ks) {
      short8 pb = *(const short8*)(Prow + ((ks * 64 + l4 * 16) ^ swz));
#pragma unroll
      for (int db = 0; db < 4; ++db) {
        short8 vf = *(const short8*)(vb[db] + k0 + ks * 32 + l4 * 8);
        oacc[db] = __builtin_amdgcn_mfma_f32_16x16x32_bf16(vf, pb, oacc[db], 0, 0, 0);
      }
    }
    __builtin_amdgcn_s_setprio(0);
    wcur = wnext;
  }

  // ---- finalize: O = O^T / l -> oh[b, s=q0+l15, h*64+d] (bf16) ----
  float rl = 1.f / l;
  u16* orow = oh + ((size_t)b * 1024 + q0 + l15) * 1024 + h * 64;
#pragma unroll
  for (int db = 0; db < 4; ++db) {
    unsigned w0 = cvtpk(oacc[db][0] * rl, oacc[db][1] * rl);
    unsigned w1 = cvtpk(oacc[db][2] * rl, oacc[db][3] * rl);
    unsigned o2[2] = {w0, w1};
    *(unsigned long long*)(orow + db * 16 + l4 * 4) = *(unsigned long long*)o2;
  }
}

// ---------- launch ----------
extern "C" void kernel_launch(void* const* d_in, const int* in_sizes, int n_in,
                              void* d_out, int out_size, void* d_ws, size_t ws_size,
                              hipStream_t stream) {
  const float* x = (const float*)d_in[0];
  const float* Wq = (const float*)d_in[1];
  const float* bq = (const float*)d_in[2];
  const float* Wk = (const float*)d_in[3];
  const float* bk = (const float*)d_in[4];
  const float* Wv = (const float*)d_in[5];
  const float* bv = (const float*)d_in[6];
  const float* Wo = (const float*)d_in[7];
  const float* bo = (const float*)d_in[8];
  const float* temp = (const float*)d_in[9];
  const void* mask = (const void*)d_in[10];

  char* ws = (char*)d_ws;
  int* flag = (int*)ws;
  u16* xb = (u16*)(ws + 256);                 // 8 MiB (x bf16; reused as oh later)
  u16* Wt = xb + (size_t)4 * 1024 * 1024;     // 8 MiB (Wq^T,Wk^T,Wv^T,Wo^T bf16)
  u16* qbuf = Wt + (size_t)4 * 1024 * 1024;   // 8 MiB [B,H,S,D]
  u16* kbuf = qbuf + (size_t)4 * 1024 * 1024; // 8 MiB [B,H,S,D]
  u16* vTb = kbuf + (size_t)4 * 1024 * 1024;  // 8 MiB [B,H,D,S]
  u64* mbits = (u64*)(vTb + (size_t)4 * 1024 * 1024);  // 8 MiB bitmask
  u16* oh = xb;                               // alias: xb dead after QKV GEMM

  detect_kernel<<<1, 256, 0, stream>>>((const unsigned char*)mask, flag);
  maskbits_kernel<<<2048, 256, 0, stream>>>(mask, flag, mbits);
  xcvt_kernel<<<4096, 256, 0, stream>>>(x, xb);
  wcvt_kernel<<<dim3(32, 32, 4), 256, 0, stream>>>(Wq, Wk, Wv, Wo, Wt);
  gemm128_kernel<<<dim3(32, 8, 3), 256, 0, stream>>>(
      xb, Wt, Wt + 1024 * 1024, Wt + 2 * 1024 * 1024,
      bq, bk, bv, qbuf, kbuf, vTb, nullptr, 0);
  attn_kernel<<<dim3(16, 64), 256, 0, stream>>>(qbuf, kbuf, vTb, mbits, temp, oh);
  gemm128_kernel<<<dim3(32, 8, 1), 256, 0, stream>>>(
      oh, Wt + 3 * 1024 * 1024, nullptr, nullptr,
      bo, nullptr, nullptr, nullptr, nullptr, nullptr, (float*)d_out, 1);
}

// Round 3
// 222.007 us; speedup vs baseline: 1.4877x; 1.4027x over previous
//
#include <hip/hip_runtime.h>

typedef unsigned short u16;
typedef short short8 __attribute__((ext_vector_type(8)));
typedef float f32x4 __attribute__((ext_vector_type(4)));
typedef float float4v __attribute__((ext_vector_type(4)));
typedef u16 u16x4 __attribute__((ext_vector_type(4)));
typedef unsigned long long u64;

// ---------- helpers ----------
__device__ __forceinline__ u16 f2bf(float f) {
  union { float f; unsigned u; } v; v.f = f;
  unsigned r = v.u + 0x7FFFu + ((v.u >> 16) & 1u);   // round-to-nearest-even
  return (u16)(r >> 16);
}

__device__ __forceinline__ unsigned cvtpk(float lo, float hi) {
  unsigned r;
  asm("v_cvt_pk_bf16_f32 %0, %1, %2" : "=v"(r) : "v"(lo), "v"(hi));
  return r;
}

__device__ __forceinline__ void gload16(const u16* g, u16* l) {
  __builtin_amdgcn_global_load_lds(
      (const __attribute__((address_space(1))) void*)g,
      (__attribute__((address_space(3))) void*)l, 16, 0, 0);
}

// ---------- mask format detection ----------
// fmt: 0 = u8/bool, 1 = i32, 2 = f32, 3 = i64
__global__ void detect_kernel(const unsigned char* __restrict__ m, int* __restrict__ flag) {
  __shared__ int f3F, fOdd, fOddD;
  if (threadIdx.x == 0) { f3F = 0; fOdd = 0; fOddD = 0; }
  __syncthreads();
  int a = 0, b = 0, c = 0;
  for (int i = threadIdx.x; i < 16384; i += 256) {
    unsigned char v = m[i];
    if (v == 0x3F) a = 1;            // f32 1.0f high byte
    if (v && (i & 3)) b = 1;         // nonzero off a dword boundary -> bytes
    if (v && ((i >> 2) & 1)) c = 1;  // nonzero in odd dword -> i32 (not i64)
  }
  if (a) atomicOr(&f3F, 1);
  if (b) atomicOr(&fOdd, 1);
  if (c) atomicOr(&fOddD, 1);
  __syncthreads();
  if (threadIdx.x == 0)
    *flag = f3F ? 2 : (fOdd ? 0 : (fOddD ? 1 : 3));
}

// ---------- mask -> bitmask, k-tile-major: word[(bh*16 + kt)*1024 + q] ----------
// bit j of word = mask[bh, q, kt*64 + j] != 0. One thread builds one word.
__global__ __launch_bounds__(256)
void maskbits_kernel(const void* __restrict__ mask, const int* __restrict__ fmtp,
                     u64* __restrict__ bits) {
  const int fmt = *fmtp;
  const int wi = blockIdx.x * 256 + threadIdx.x;  // 1M words total
  u64 b = 0;
  if (fmt == 0) {
    const uint4* mp = (const uint4*)mask + (size_t)wi * 4;
#pragma unroll
    for (int i = 0; i < 4; ++i) {
      uint4 v = mp[i];
      unsigned x[4] = {v.x, v.y, v.z, v.w};
#pragma unroll
      for (int d = 0; d < 4; ++d)
#pragma unroll
        for (int by = 0; by < 4; ++by)
          if (x[d] & (0xFFu << (by * 8))) b |= 1ULL << (i * 16 + d * 4 + by);
    }
  } else if (fmt != 3) {  // 4-byte elements (i32 / f32): bits-nonzero test
    const uint4* mp = (const uint4*)mask + (size_t)wi * 16;
#pragma unroll
    for (int i = 0; i < 16; ++i) {
      uint4 v = mp[i];
      if (v.x) b |= 1ULL << (i * 4 + 0);
      if (v.y) b |= 1ULL << (i * 4 + 1);
      if (v.z) b |= 1ULL << (i * 4 + 2);
      if (v.w) b |= 1ULL << (i * 4 + 3);
    }
  } else {  // i64
    const uint4* mp = (const uint4*)mask + (size_t)wi * 32;
#pragma unroll
    for (int i = 0; i < 32; ++i) {
      uint4 v = mp[i];
      if (v.x | v.y) b |= 1ULL << (i * 2 + 0);
      if (v.z | v.w) b |= 1ULL << (i * 2 + 1);
    }
  }
  int bh = wi >> 14, q = (wi >> 4) & 1023, kt = wi & 15;
  bits[((size_t)bh * 16 + kt) * 1024 + q] = b;
}

// ---------- x: f32 -> bf16, straight copy ----------
__global__ __launch_bounds__(256) void xcvt_kernel(const float* __restrict__ x, u16* __restrict__ xb) {
  int i = (blockIdx.x * 256 + threadIdx.x) * 4;
  float4v v = *(const float4v*)(x + i);
  u16x4 o;
  o[0] = f2bf(v[0]); o[1] = f2bf(v[1]); o[2] = f2bf(v[2]); o[3] = f2bf(v[3]);
  *(u16x4*)(xb + i) = o;
}

// ---------- W: f32 [K][N] -> bf16 transposed [N][K] (4 weights via blockIdx.z) ----------
__global__ __launch_bounds__(256) void wcvt_kernel(
    const float* __restrict__ W0, const float* __restrict__ W1,
    const float* __restrict__ W2, const float* __restrict__ W3,
    u16* __restrict__ Wt) {
  __shared__ float t[32][33];
  int z = blockIdx.z;
  const float* W = (z == 0) ? W0 : (z == 1) ? W1 : (z == 2) ? W2 : W3;
  u16* out = Wt + (size_t)z * 1024 * 1024;
  int n0 = blockIdx.x * 32, k0 = blockIdx.y * 32;
  int tx = threadIdx.x & 31, ty = threadIdx.x >> 5;
#pragma unroll
  for (int j = 0; j < 4; ++j)
    t[ty + 8 * j][tx] = W[(size_t)(k0 + ty + 8 * j) * 1024 + n0 + tx];
  __syncthreads();
#pragma unroll
  for (int j = 0; j < 4; ++j)
    out[(size_t)(n0 + ty + 8 * j) * 1024 + k0 + tx] = f2bf(t[tx][ty + 8 * j]);
}

// ---------- 128x128 bf16 GEMM, A[M][K] x Bt[N][K]^T + bias ----------
__global__ __launch_bounds__(256)
void gemm128_kernel(const u16* __restrict__ A,
                    const u16* __restrict__ BtQ, const u16* __restrict__ BtK, const u16* __restrict__ BtV,
                    const float* __restrict__ bQ, const float* __restrict__ bK, const float* __restrict__ bV,
                    u16* __restrict__ qb, u16* __restrict__ kb, u16* __restrict__ vT,
                    float* __restrict__ fo, int phase) {
  constexpr int K = 1024;
  __shared__ u16 As[128 * 32];
  __shared__ u16 Bs[128 * 32];
  const int tid = threadIdx.x;
  const int lane = tid & 63, w = tid >> 6;
  const int l15 = lane & 15, l4 = lane >> 4;
  const int m0 = blockIdx.x * 128, n0 = blockIdx.y * 128;
  const int z = blockIdx.z;
  const u16* Bt = (z == 0) ? BtQ : (z == 1) ? BtK : BtV;
  const float* bias = (z == 0) ? bQ : (z == 1) ? bK : bV;
  const int wr = w >> 1, wc = w & 1;

  f32x4 acc[4][4] = {};

  const int c0 = tid, c1 = 256 + tid;
  const u16* ga0 = A + (size_t)(m0 + (c0 >> 2)) * K + (c0 & 3) * 8;
  const u16* ga1 = A + (size_t)(m0 + (c1 >> 2)) * K + (c1 & 3) * 8;
  const u16* gb0 = Bt + (size_t)(n0 + (c0 >> 2)) * K + (c0 & 3) * 8;
  const u16* gb1 = Bt + (size_t)(n0 + (c1 >> 2)) * K + (c1 & 3) * 8;
  u16* la0 = As + c0 * 8;
  u16* la1 = As + c1 * 8;
  u16* lb0 = Bs + c0 * 8;
  u16* lb1 = Bs + c1 * 8;

  for (int kt = 0; kt < K; kt += 32) {
    gload16(ga0 + kt, la0);
    gload16(ga1 + kt, la1);
    gload16(gb0 + kt, lb0);
    gload16(gb1 + kt, lb1);
    __syncthreads();
    short8 af[4], bfr[4];
#pragma unroll
    for (int r = 0; r < 4; ++r)
      af[r] = *(const short8*)(As + (wr * 64 + r * 16 + l15) * 32 + l4 * 8);
#pragma unroll
    for (int c = 0; c < 4; ++c)
      bfr[c] = *(const short8*)(Bs + (wc * 64 + c * 16 + l15) * 32 + l4 * 8);
#pragma unroll
    for (int r = 0; r < 4; ++r)
#pragma unroll
      for (int c = 0; c < 4; ++c)
        acc[r][c] = __builtin_amdgcn_mfma_f32_16x16x32_bf16(af[r], bfr[c], acc[r][c], 0, 0, 0);
    __syncthreads();
  }

  float bv4[4];
#pragma unroll
  for (int c = 0; c < 4; ++c) bv4[c] = bias[n0 + wc * 64 + c * 16 + l15];

#pragma unroll
  for (int r = 0; r < 4; ++r) {
#pragma unroll
    for (int c = 0; c < 4; ++c) {
#pragma unroll
      for (int j = 0; j < 4; ++j) {
        float val = acc[r][c][j] + bv4[c];
        int row = m0 + wr * 64 + r * 16 + l4 * 4 + j;  // m index (= b*1024+s)
        int col = n0 + wc * 64 + c * 16 + l15;         // n index (= h*64+d)
        if (phase == 0) {
          int b = row >> 10, s = row & 1023, hh = col >> 6, d = col & 63;
          if (z < 2) {
            u16* dst = (z == 0) ? qb : kb;
            dst[(((size_t)b * 16 + hh) * 1024 + s) * 64 + d] = f2bf(val);
          } else {
            vT[(((size_t)b * 16 + hh) * 64 + d) * 1024 + s] = f2bf(val);
          }
        } else {
          fo[(size_t)row * 1024 + col] = val;
        }
      }
    }
  }
}

// ---------- flash attention, LDS-staged K/V (m97 structure), swapped QK^T ----------
// Block: 4 waves share bh; each wave owns 16 q-rows. K/V tiles (64x64 bf16 each)
// double-buffered in LDS via global_load_lds with inverse-swizzled SOURCE
// addresses (rule 21): LDS dest linear, reads XOR-swizzled -> bank-floor.
__global__ __launch_bounds__(256)
void attn_kernel(const u16* __restrict__ qb, const u16* __restrict__ kb, const u16* __restrict__ vT,
                 const u64* __restrict__ mbits, const float* __restrict__ temp,
                 u16* __restrict__ oh) {
  __shared__ u16 Ks[2][64 * 64];   // 16 KiB
  __shared__ u16 Vs[2][64 * 64];   // 16 KiB
  __shared__ u16 P[4][16 * 64];    //  8 KiB (per-wave P round-trip)
  const int tid = threadIdx.x, lane = tid & 63, w = tid >> 6;
  const int l15 = lane & 15, l4 = lane >> 4;
  const int bh = blockIdx.y, b = bh >> 4, h = bh & 15;
  const int q0 = blockIdx.x * 64 + w * 16;
  const u16* qp = qb + ((size_t)bh * 1024 + q0) * 64;
  const u16* kp = kb + (size_t)bh * 1024 * 64;
  const u16* vp = vT + (size_t)bh * 64 * 1024;
  const float sc2 = temp[h] * 0.125f * 1.4426950408889634f;  // temp/sqrt(64)*log2(e)
  char* Pw = (char*)&P[w][0];
  const int swzP = (l15 & 7) << 4;   // byte-XOR for P round-trip
  const int swzK = (l15 & 7) << 3;   // u16-index XOR for K/V LDS reads
  char* Prow = Pw + l15 * 128;

  // chunk coords for staging (two 16B chunks per thread per buffer)
  const int L0 = tid, L1 = tid + 256;
  const int r0 = L0 >> 3, cc0 = (L0 & 7) ^ (r0 & 7);
  const int r1 = L1 >> 3, cc1 = (L1 & 7) ^ (r1 & 7);

  // Q as B-fragment: col = q = l15, k-slice = l4*8
  short8 qf0 = *(const short8*)(qp + (size_t)l15 * 64 + l4 * 8);
  short8 qf1 = *(const short8*)(qp + (size_t)l15 * 64 + 32 + l4 * 8);

  float m = -1e30f, l = 0.f;
  f32x4 oacc[4] = {};  // O^T: row d = db*16 + l4*4 + j, col q = l15

  const u64* mb = mbits + (size_t)bh * 16 * 1024 + q0 + l15;
  u64 wcur = mb[0];

  // prologue: stage tile 0 into buf 0
  {
    gload16(kp + (size_t)r0 * 64 + cc0 * 8, &Ks[0][L0 * 8]);
    gload16(kp + (size_t)r1 * 64 + cc1 * 8, &Ks[0][L1 * 8]);
    gload16(vp + (size_t)r0 * 1024 + cc0 * 8, &Vs[0][L0 * 8]);
    gload16(vp + (size_t)r1 * 1024 + cc1 * 8, &Vs[0][L1 * 8]);
  }

  for (int t = 0; t < 16; ++t) {
    const int buf = t & 1;
    __syncthreads();  // stage(t) drained (compiler emits vmcnt(0) before barrier)

    if (t < 15) {  // stage tile t+1 into buf^1 (hides under compute of t)
      const int k1 = (t + 1) * 64;
      gload16(kp + (size_t)(k1 + r0) * 64 + cc0 * 8, &Ks[buf ^ 1][L0 * 8]);
      gload16(kp + (size_t)(k1 + r1) * 64 + cc1 * 8, &Ks[buf ^ 1][L1 * 8]);
      gload16(vp + (size_t)r0 * 1024 + k1 + cc0 * 8, &Vs[buf ^ 1][L0 * 8]);
      gload16(vp + (size_t)r1 * 1024 + k1 + cc1 * 8, &Vs[buf ^ 1][L1 * 8]);
    }
    u64 wnext = (t < 15) ? mb[(t + 1) * 1024] : 0ULL;

    // ---- S^T = K Q^T from LDS ----
    f32x4 s[4] = {};
    __builtin_amdgcn_s_setprio(1);
#pragma unroll
    for (int cb = 0; cb < 4; ++cb) {
      const u16* kr = &Ks[buf][(cb * 16 + l15) * 64];
      short8 kf0 = *(const short8*)(kr + ((l4 * 8) ^ swzK));
      short8 kf1 = *(const short8*)(kr + ((32 + l4 * 8) ^ swzK));
      s[cb] = __builtin_amdgcn_mfma_f32_16x16x32_bf16(kf0, qf0, s[cb], 0, 0, 0);
      s[cb] = __builtin_amdgcn_mfma_f32_16x16x32_bf16(kf1, qf1, s[cb], 0, 0, 0);
    }
    __builtin_amdgcn_s_setprio(0);

    // ---- mask + lane-local online softmax (all 16 scores belong to q=l15) ----
    float xx[4][4];
#pragma unroll
    for (int cb = 0; cb < 4; ++cb) {
      unsigned nib = (unsigned)(wcur >> (cb * 16 + l4 * 4)) & 15u;
#pragma unroll
      for (int j = 0; j < 4; ++j)
        xx[cb][j] = ((nib >> j) & 1) ? s[cb][j] * sc2 : -1e30f;
    }
    float mt = xx[0][0];
#pragma unroll
    for (int cb = 0; cb < 4; ++cb)
#pragma unroll
      for (int j = 0; j < 4; ++j) mt = fmaxf(mt, xx[cb][j]);
    mt = fmaxf(mt, __shfl_xor(mt, 16));
    mt = fmaxf(mt, __shfl_xor(mt, 32));
    float mnew = fmaxf(m, mt);
    float al = exp2f(m - mnew);
    float rs = 0.f;
#pragma unroll
    for (int cb = 0; cb < 4; ++cb)
#pragma unroll
      for (int j = 0; j < 4; ++j) {
        xx[cb][j] = exp2f(xx[cb][j] - mnew);
        rs += xx[cb][j];
      }
    rs += __shfl_xor(rs, 16);
    rs += __shfl_xor(rs, 32);
    l = l * al + rs;
    m = mnew;
#pragma unroll
    for (int db = 0; db < 4; ++db) oacc[db] *= al;

    // ---- P -> LDS (per-wave, XOR-swizzled) and back as B-frag ----
#pragma unroll
    for (int cb = 0; cb < 4; ++cb) {
      unsigned w0 = cvtpk(xx[cb][0], xx[cb][1]);
      unsigned w1 = cvtpk(xx[cb][2], xx[cb][3]);
      unsigned o2[2] = {w0, w1};
      *(unsigned long long*)(Prow + ((cb * 32 + l4 * 8) ^ swzP)) = *(unsigned long long*)o2;
    }

    // ---- O^T += V^T P^T from LDS ----
    __builtin_amdgcn_s_setprio(1);
#pragma unroll
    for (int ks = 0; ks < 2; ++ks) {
      short8 pb = *(const short8*)(Prow + ((ks * 64 + l4 * 16) ^ swzP));
#pragma unroll
      for (int db = 0; db < 4; ++db) {
        short8 vf = *(const short8*)(&Vs[buf][(db * 16 + l15) * 64 + ((ks * 32 + l4 * 8) ^ swzK)]);
        oacc[db] = __builtin_amdgcn_mfma_f32_16x16x32_bf16(vf, pb, oacc[db], 0, 0, 0);
      }
    }
    __builtin_amdgcn_s_setprio(0);
    wcur = wnext;
  }

  // ---- finalize: O = O^T / l -> oh[b, s=q0+l15, h*64+d] (bf16) ----
  float rl = 1.f / l;
  u16* orow = oh + ((size_t)b * 1024 + q0 + l15) * 1024 + h * 64;
#pragma unroll
  for (int db = 0; db < 4; ++db) {
    unsigned w0 = cvtpk(oacc[db][0] * rl, oacc[db][1] * rl);
    unsigned w1 = cvtpk(oacc[db][2] * rl, oacc[db][3] * rl);
    unsigned o2[2] = {w0, w1};
    *(unsigned long long*)(orow + db * 16 + l4 * 4) = *(unsigned long long*)o2;
  }
}

// ---------- launch ----------
extern "C" void kernel_launch(void* const* d_in, const int* in_sizes, int n_in,
                              void* d_out, int out_size, void* d_ws, size_t ws_size,
                              hipStream_t stream) {
  const float* x = (const float*)d_in[0];
  const float* Wq = (const float*)d_in[1];
  const float* bq = (const float*)d_in[2];
  const float* Wk = (const float*)d_in[3];
  const float* bk = (const float*)d_in[4];
  const float* Wv = (const float*)d_in[5];
  const float* bv = (const float*)d_in[6];
  const float* Wo = (const float*)d_in[7];
  const float* bo = (const float*)d_in[8];
  const float* temp = (const float*)d_in[9];
  const void* mask = (const void*)d_in[10];

  char* ws = (char*)d_ws;
  int* flag = (int*)ws;
  u16* xb = (u16*)(ws + 256);                 // 8 MiB (x bf16; reused as oh later)
  u16* Wt = xb + (size_t)4 * 1024 * 1024;     // 8 MiB (Wq^T,Wk^T,Wv^T,Wo^T bf16)
  u16* qbuf = Wt + (size_t)4 * 1024 * 1024;   // 8 MiB [B,H,S,D]
  u16* kbuf = qbuf + (size_t)4 * 1024 * 1024; // 8 MiB [B,H,S,D]
  u16* vTb = kbuf + (size_t)4 * 1024 * 1024;  // 8 MiB [B,H,D,S]
  u64* mbits = (u64*)(vTb + (size_t)4 * 1024 * 1024);  // 8 MiB bitmask
  u16* oh = xb;                               // alias: xb dead after QKV GEMM

  detect_kernel<<<1, 256, 0, stream>>>((const unsigned char*)mask, flag);
  maskbits_kernel<<<4096, 256, 0, stream>>>(mask, flag, mbits);
  xcvt_kernel<<<4096, 256, 0, stream>>>(x, xb);
  wcvt_kernel<<<dim3(32, 32, 4), 256, 0, stream>>>(Wq, Wk, Wv, Wo, Wt);
  gemm128_kernel<<<dim3(32, 8, 3), 256, 0, stream>>>(
      xb, Wt, Wt + 1024 * 1024, Wt + 2 * 1024 * 1024,
      bq, bk, bv, qbuf, kbuf, vTb, nullptr, 0);
  attn_kernel<<<dim3(16, 64), 256, 0, stream>>>(qbuf, kbuf, vTb, mbits, temp, oh);
  gemm128_kernel<<<dim3(32, 8, 1), 256, 0, stream>>>(
      oh, Wt + 3 * 1024 * 1024, nullptr, nullptr,
      bo, nullptr, nullptr, nullptr, nullptr, nullptr, (float*)d_out, 1);
}

// Round 4
// 193.136 us; speedup vs baseline: 1.7101x; 1.1495x over previous
//
#include <hip/hip_runtime.h>

typedef unsigned short u16;
typedef short short8 __attribute__((ext_vector_type(8)));
typedef float f32x4 __attribute__((ext_vector_type(4)));
typedef float float4v __attribute__((ext_vector_type(4)));
typedef u16 u16x4 __attribute__((ext_vector_type(4)));
typedef unsigned long long u64;

// ---------- helpers ----------
__device__ __forceinline__ u16 f2bf(float f) {
  union { float f; unsigned u; } v; v.f = f;
  unsigned r = v.u + 0x7FFFu + ((v.u >> 16) & 1u);   // round-to-nearest-even
  return (u16)(r >> 16);
}

__device__ __forceinline__ unsigned cvtpk(float lo, float hi) {
  unsigned r;
  asm("v_cvt_pk_bf16_f32 %0, %1, %2" : "=v"(r) : "v"(lo), "v"(hi));
  return r;
}

__device__ __forceinline__ void gload16(const u16* g, u16* l) {
  __builtin_amdgcn_global_load_lds(
      (const __attribute__((address_space(1))) void*)g,
      (__attribute__((address_space(3))) void*)l, 16, 0, 0);
}

// ---------- mask -> bitmask, k-tile-major: word[(bh*16 + kt)*1024 + q] ----------
// Self-detects mask dtype from first 4KB. fmt: 0=u8, 1=i32, 2=f32, 3=i64.
__global__ __launch_bounds__(256)
void maskbits_kernel(const void* __restrict__ mask, u64* __restrict__ bits) {
  __shared__ int sf;
  if (threadIdx.x == 0) sf = 0;
  __syncthreads();
  {
    uint4 v = ((const uint4*)mask)[threadIdx.x];
    unsigned xs[4] = {v.x, v.y, v.z, v.w};
    int f = 0;
#pragma unroll
    for (int d = 0; d < 4; ++d) {
      unsigned u = xs[d];
      if (u == 0x3F800000u) f |= 1;   // f32 1.0
      if (u & 0xFFFFFF00u) f |= 2;    // nonzero byte off dword base -> u8
      if ((d & 1) && u) f |= 4;       // nonzero odd dword -> i32
    }
    if (f) atomicOr(&sf, f);
  }
  __syncthreads();
  const int fl = sf;
  const int fmt = (fl & 1) ? 2 : ((fl & 2) ? 0 : ((fl & 4) ? 1 : 3));

  const int wi = blockIdx.x * 256 + threadIdx.x;  // 1M words total
  u64 b = 0;
  if (fmt == 0) {
    const uint4* mp = (const uint4*)mask + (size_t)wi * 4;
#pragma unroll
    for (int i = 0; i < 4; ++i) {
      uint4 v = mp[i];
      unsigned x[4] = {v.x, v.y, v.z, v.w};
#pragma unroll
      for (int d = 0; d < 4; ++d)
#pragma unroll
        for (int by = 0; by < 4; ++by)
          if (x[d] & (0xFFu << (by * 8))) b |= 1ULL << (i * 16 + d * 4 + by);
    }
  } else if (fmt != 3) {  // 4-byte elements (i32 / f32)
    const uint4* mp = (const uint4*)mask + (size_t)wi * 16;
#pragma unroll
    for (int i = 0; i < 16; ++i) {
      uint4 v = mp[i];
      if (v.x) b |= 1ULL << (i * 4 + 0);
      if (v.y) b |= 1ULL << (i * 4 + 1);
      if (v.z) b |= 1ULL << (i * 4 + 2);
      if (v.w) b |= 1ULL << (i * 4 + 3);
    }
  } else {  // i64
    const uint4* mp = (const uint4*)mask + (size_t)wi * 32;
#pragma unroll
    for (int i = 0; i < 32; ++i) {
      uint4 v = mp[i];
      if (v.x | v.y) b |= 1ULL << (i * 2 + 0);
      if (v.z | v.w) b |= 1ULL << (i * 2 + 1);
    }
  }
  int bh = wi >> 14, q = (wi >> 4) & 1023, kt = wi & 15;
  bits[((size_t)bh * 16 + kt) * 1024 + q] = b;
}

// ---------- x: f32 -> bf16, straight copy ----------
__global__ __launch_bounds__(256) void xcvt_kernel(const float* __restrict__ x, u16* __restrict__ xb) {
  int i = (blockIdx.x * 256 + threadIdx.x) * 4;
  float4v v = *(const float4v*)(x + i);
  u16x4 o;
  o[0] = f2bf(v[0]); o[1] = f2bf(v[1]); o[2] = f2bf(v[2]); o[3] = f2bf(v[3]);
  *(u16x4*)(xb + i) = o;
}

// ---------- W: f32 [K][N] -> bf16 transposed [N][K] (4 weights via blockIdx.z) ----------
__global__ __launch_bounds__(256) void wcvt_kernel(
    const float* __restrict__ W0, const float* __restrict__ W1,
    const float* __restrict__ W2, const float* __restrict__ W3,
    u16* __restrict__ Wt) {
  __shared__ float t[32][33];
  int z = blockIdx.z;
  const float* W = (z == 0) ? W0 : (z == 1) ? W1 : (z == 2) ? W2 : W3;
  u16* out = Wt + (size_t)z * 1024 * 1024;
  int n0 = blockIdx.x * 32, k0 = blockIdx.y * 32;
  int tx = threadIdx.x & 31, ty = threadIdx.x >> 5;
#pragma unroll
  for (int j = 0; j < 4; ++j)
    t[ty + 8 * j][tx] = W[(size_t)(k0 + ty + 8 * j) * 1024 + n0 + tx];
  __syncthreads();
#pragma unroll
  for (int j = 0; j < 4; ++j)
    out[(size_t)(n0 + ty + 8 * j) * 1024 + k0 + tx] = f2bf(t[tx][ty + 8 * j]);
}

// ---------- 128x128 bf16 GEMM, A[M][K] x Bt[N][K]^T + bias ----------
// phase 0, z==0: q output pre-scaled by temp[h]/sqrt(D)*log2(e)
__global__ __launch_bounds__(256)
void gemm128_kernel(const u16* __restrict__ A,
                    const u16* __restrict__ BtQ, const u16* __restrict__ BtK, const u16* __restrict__ BtV,
                    const float* __restrict__ bQ, const float* __restrict__ bK, const float* __restrict__ bV,
                    const float* __restrict__ temp,
                    u16* __restrict__ qb, u16* __restrict__ kb, u16* __restrict__ vT,
                    float* __restrict__ fo, int phase) {
  constexpr int K = 1024;
  __shared__ u16 As[128 * 32];
  __shared__ u16 Bs[128 * 32];
  const int tid = threadIdx.x;
  const int lane = tid & 63, w = tid >> 6;
  const int l15 = lane & 15, l4 = lane >> 4;
  const int m0 = blockIdx.x * 128, n0 = blockIdx.y * 128;
  const int z = blockIdx.z;
  const u16* Bt = (z == 0) ? BtQ : (z == 1) ? BtK : BtV;
  const float* bias = (z == 0) ? bQ : (z == 1) ? bK : bV;
  const int wr = w >> 1, wc = w & 1;

  f32x4 acc[4][4] = {};

  const int c0 = tid, c1 = 256 + tid;
  const u16* ga0 = A + (size_t)(m0 + (c0 >> 2)) * K + (c0 & 3) * 8;
  const u16* ga1 = A + (size_t)(m0 + (c1 >> 2)) * K + (c1 & 3) * 8;
  const u16* gb0 = Bt + (size_t)(n0 + (c0 >> 2)) * K + (c0 & 3) * 8;
  const u16* gb1 = Bt + (size_t)(n0 + (c1 >> 2)) * K + (c1 & 3) * 8;
  u16* la0 = As + c0 * 8;
  u16* la1 = As + c1 * 8;
  u16* lb0 = Bs + c0 * 8;
  u16* lb1 = Bs + c1 * 8;

  for (int kt = 0; kt < K; kt += 32) {
    gload16(ga0 + kt, la0);
    gload16(ga1 + kt, la1);
    gload16(gb0 + kt, lb0);
    gload16(gb1 + kt, lb1);
    __syncthreads();
    short8 af[4], bfr[4];
#pragma unroll
    for (int r = 0; r < 4; ++r)
      af[r] = *(const short8*)(As + (wr * 64 + r * 16 + l15) * 32 + l4 * 8);
#pragma unroll
    for (int c = 0; c < 4; ++c)
      bfr[c] = *(const short8*)(Bs + (wc * 64 + c * 16 + l15) * 32 + l4 * 8);
#pragma unroll
    for (int r = 0; r < 4; ++r)
#pragma unroll
      for (int c = 0; c < 4; ++c)
        acc[r][c] = __builtin_amdgcn_mfma_f32_16x16x32_bf16(af[r], bfr[c], acc[r][c], 0, 0, 0);
    __syncthreads();
  }

  float bv4[4], fac4[4];
#pragma unroll
  for (int c = 0; c < 4; ++c) {
    int col = n0 + wc * 64 + c * 16 + l15;
    bv4[c] = bias[col];
    fac4[c] = (phase == 0 && z == 0) ? temp[col >> 6] * 0.18033688011112042f : 1.0f;
  }

#pragma unroll
  for (int r = 0; r < 4; ++r) {
#pragma unroll
    for (int c = 0; c < 4; ++c) {
#pragma unroll
      for (int j = 0; j < 4; ++j) {
        float val = (acc[r][c][j] + bv4[c]) * fac4[c];
        int row = m0 + wr * 64 + r * 16 + l4 * 4 + j;  // m index (= b*1024+s)
        int col = n0 + wc * 64 + c * 16 + l15;         // n index (= h*64+d)
        if (phase == 0) {
          int b = row >> 10, s = row & 1023, hh = col >> 6, d = col & 63;
          if (z < 2) {
            u16* dst = (z == 0) ? qb : kb;
            dst[(((size_t)b * 16 + hh) * 1024 + s) * 64 + d] = f2bf(val);
          } else {
            vT[(((size_t)b * 16 + hh) * 64 + d) * 1024 + s] = f2bf(val);
          }
        } else {
          fo[(size_t)row * 1024 + col] = val;
        }
      }
    }
  }
}

// ---------- per-q-group masked online softmax + P write (scores pre-scaled) ----------
__device__ __forceinline__ void softmax_pwrite(const f32x4* s, u64 wcur,
                                               float& m, float& l, f32x4* oacc,
                                               char* Prow, int swzP, int l4) {
  float xx[4][4];
#pragma unroll
  for (int cb = 0; cb < 4; ++cb) {
    unsigned nib = (unsigned)(wcur >> (cb * 16 + l4 * 4)) & 15u;
#pragma unroll
    for (int j = 0; j < 4; ++j)
      xx[cb][j] = ((nib >> j) & 1) ? s[cb][j] : -1e30f;
  }
  float mt = xx[0][0];
#pragma unroll
  for (int cb = 0; cb < 4; ++cb)
#pragma unroll
    for (int j = 0; j < 4; ++j) mt = fmaxf(mt, xx[cb][j]);
  mt = fmaxf(mt, __shfl_xor(mt, 16));
  mt = fmaxf(mt, __shfl_xor(mt, 32));
  if (!__all(mt <= m + 8.f)) {   // T13 defer-max: skip rescale on small drift
    float mnew = fmaxf(m, mt);
    float al = exp2f(m - mnew);
    l *= al;
#pragma unroll
    for (int db = 0; db < 4; ++db) oacc[db] *= al;
    m = mnew;
  }
  float rs = 0.f;
#pragma unroll
  for (int cb = 0; cb < 4; ++cb)
#pragma unroll
    for (int j = 0; j < 4; ++j) {
      xx[cb][j] = exp2f(xx[cb][j] - m);
      rs += xx[cb][j];
    }
  rs += __shfl_xor(rs, 16);
  rs += __shfl_xor(rs, 32);
  l += rs;
#pragma unroll
  for (int cb = 0; cb < 4; ++cb) {
    unsigned w0 = cvtpk(xx[cb][0], xx[cb][1]);
    unsigned w1 = cvtpk(xx[cb][2], xx[cb][3]);
    unsigned o2[2] = {w0, w1};
    *(unsigned long long*)(Prow + ((cb * 32 + l4 * 8) ^ swzP)) = *(unsigned long long*)o2;
  }
}

// ---------- flash attention, LDS-staged K/V, QBLK=32/wave, swapped QK^T ----------
// 4 waves/block share bh; each wave owns 32 q-rows (2 q-groups of 16 reusing
// the same K/V register fragments). XCD-bijective swizzle keeps one bh's
// 8 q-blocks on one XCD (K/V 256KB -> L2-resident per XCD).
__global__ __launch_bounds__(256)
void attn_kernel(const u16* __restrict__ qb, const u16* __restrict__ kb, const u16* __restrict__ vT,
                 const u64* __restrict__ mbits, u16* __restrict__ oh) {
  __shared__ u16 Ks[2][64 * 64];   // 16 KiB
  __shared__ u16 Vs[2][64 * 64];   // 16 KiB
  __shared__ u16 P[4][32 * 64];    // 16 KiB (per-wave 32q x 64k)
  const int tid = threadIdx.x, lane = tid & 63, w = tid >> 6;
  const int l15 = lane & 15, l4 = lane >> 4;
  const int id = blockIdx.x;           // 512 blocks: 8 xcd x 8 bh x 8 qx
  const int xcd = id & 7, sl = id >> 3;
  const int bh = xcd * 8 + (sl >> 3), qx = sl & 7;
  const int b = bh >> 4, h = bh & 15;
  const int q0 = qx * 128 + w * 32;
  const u16* qp = qb + ((size_t)bh * 1024 + q0) * 64;
  const u16* kp = kb + (size_t)bh * 1024 * 64;
  const u16* vp = vT + (size_t)bh * 64 * 1024;
  char* Pw = (char*)&P[w][0];
  const int swzP = (l15 & 7) << 4;
  char* ProwA = Pw + l15 * 128;
  char* ProwB = Pw + (16 + l15) * 128;

  // staging coords (two 16B chunks per thread per K/V buffer, inverse-swizzled src)
  const int L0 = tid, L1 = tid + 256;
  const int r0 = L0 >> 3, cc0 = (L0 & 7) ^ (r0 & 7);
  const int r1 = L1 >> 3, cc1 = (L1 & 7) ^ (r1 & 7);
  const int swzK = (l15 & 7) << 3;   // u16-index XOR for K/V LDS reads

  // Q fragments (pre-scaled by temp/sqrt(D)*log2e in GEMM epilogue)
  short8 qa0 = *(const short8*)(qp + (size_t)l15 * 64 + l4 * 8);
  short8 qa1 = *(const short8*)(qp + (size_t)l15 * 64 + 32 + l4 * 8);
  short8 qb0 = *(const short8*)(qp + (size_t)(16 + l15) * 64 + l4 * 8);
  short8 qb1 = *(const short8*)(qp + (size_t)(16 + l15) * 64 + 32 + l4 * 8);

  float ma = -1e30f, la = 0.f, mb_ = -1e30f, lb = 0.f;
  f32x4 oa[4] = {}, ob[4] = {};   // O^T: row d = db*16+l4*4+j, col q = l15

  const u64* mba = mbits + (size_t)bh * 16 * 1024 + q0 + l15;
  u64 wa = mba[0], wb = mba[16];

  // prologue: stage tile 0 into buf 0
  gload16(kp + (size_t)r0 * 64 + cc0 * 8, &Ks[0][L0 * 8]);
  gload16(kp + (size_t)r1 * 64 + cc1 * 8, &Ks[0][L1 * 8]);
  gload16(vp + (size_t)r0 * 1024 + cc0 * 8, &Vs[0][L0 * 8]);
  gload16(vp + (size_t)r1 * 1024 + cc1 * 8, &Vs[0][L1 * 8]);

  for (int t = 0; t < 16; ++t) {
    const int buf = t & 1;
    __syncthreads();  // stage(t) drained (vmcnt(0) before barrier)

    if (t < 15) {  // stage tile t+1 into buf^1 (hidden under compute of t)
      const int k1 = (t + 1) * 64;
      gload16(kp + (size_t)(k1 + r0) * 64 + cc0 * 8, &Ks[buf ^ 1][L0 * 8]);
      gload16(kp + (size_t)(k1 + r1) * 64 + cc1 * 8, &Ks[buf ^ 1][L1 * 8]);
      gload16(vp + (size_t)r0 * 1024 + k1 + cc0 * 8, &Vs[buf ^ 1][L0 * 8]);
      gload16(vp + (size_t)r1 * 1024 + k1 + cc1 * 8, &Vs[buf ^ 1][L1 * 8]);
    }
    u64 wan = 0, wbn = 0;
    if (t < 15) { wan = mba[(t + 1) * 1024]; wbn = mba[(t + 1) * 1024 + 16]; }

    // ---- S^T = K Q^T for both q-groups, K-frags reused ----
    f32x4 sa[4] = {}, sb[4] = {};
    __builtin_amdgcn_s_setprio(1);
#pragma unroll
    for (int cb = 0; cb < 4; ++cb) {
      const u16* kr = &Ks[buf][(cb * 16 + l15) * 64];
      short8 kf0 = *(const short8*)(kr + ((l4 * 8) ^ swzK));
      short8 kf1 = *(const short8*)(kr + ((32 + l4 * 8) ^ swzK));
      sa[cb] = __builtin_amdgcn_mfma_f32_16x16x32_bf16(kf0, qa0, sa[cb], 0, 0, 0);
      sa[cb] = __builtin_amdgcn_mfma_f32_16x16x32_bf16(kf1, qa1, sa[cb], 0, 0, 0);
      sb[cb] = __builtin_amdgcn_mfma_f32_16x16x32_bf16(kf0, qb0, sb[cb], 0, 0, 0);
      sb[cb] = __builtin_amdgcn_mfma_f32_16x16x32_bf16(kf1, qb1, sb[cb], 0, 0, 0);
    }
    __builtin_amdgcn_s_setprio(0);

    // ---- masked online softmax + P writes (both groups) ----
    softmax_pwrite(sa, wa, ma, la, oa, ProwA, swzP, l4);
    softmax_pwrite(sb, wb, mb_, lb, ob, ProwB, swzP, l4);

    // ---- O^T += V^T P^T, V-frags reused across q-groups ----
    __builtin_amdgcn_s_setprio(1);
#pragma unroll
    for (int ks = 0; ks < 2; ++ks) {
      short8 pa = *(const short8*)(ProwA + ((ks * 64 + l4 * 16) ^ swzP));
      short8 pb = *(const short8*)(ProwB + ((ks * 64 + l4 * 16) ^ swzP));
#pragma unroll
      for (int db = 0; db < 4; ++db) {
        short8 vf = *(const short8*)(&Vs[buf][(db * 16 + l15) * 64 + ((ks * 32 + l4 * 8) ^ swzK)]);
        oa[db] = __builtin_amdgcn_mfma_f32_16x16x32_bf16(vf, pa, oa[db], 0, 0, 0);
        ob[db] = __builtin_amdgcn_mfma_f32_16x16x32_bf16(vf, pb, ob[db], 0, 0, 0);
      }
    }
    __builtin_amdgcn_s_setprio(0);
    wa = wan; wb = wbn;
  }

  // ---- finalize: O = O^T / l -> oh[b, s, h*64+d] (bf16) ----
  float rla = 1.f / la, rlb = 1.f / lb;
  u16* orowA = oh + ((size_t)b * 1024 + q0 + l15) * 1024 + h * 64;
  u16* orowB = oh + ((size_t)b * 1024 + q0 + 16 + l15) * 1024 + h * 64;
#pragma unroll
  for (int db = 0; db < 4; ++db) {
    unsigned a0 = cvtpk(oa[db][0] * rla, oa[db][1] * rla);
    unsigned a1 = cvtpk(oa[db][2] * rla, oa[db][3] * rla);
    unsigned b0 = cvtpk(ob[db][0] * rlb, ob[db][1] * rlb);
    unsigned b1 = cvtpk(ob[db][2] * rlb, ob[db][3] * rlb);
    unsigned oA[2] = {a0, a1}, oB[2] = {b0, b1};
    *(unsigned long long*)(orowA + db * 16 + l4 * 4) = *(unsigned long long*)oA;
    *(unsigned long long*)(orowB + db * 16 + l4 * 4) = *(unsigned long long*)oB;
  }
}

// ---------- launch ----------
extern "C" void kernel_launch(void* const* d_in, const int* in_sizes, int n_in,
                              void* d_out, int out_size, void* d_ws, size_t ws_size,
                              hipStream_t stream) {
  const float* x = (const float*)d_in[0];
  const float* Wq = (const float*)d_in[1];
  const float* bq = (const float*)d_in[2];
  const float* Wk = (const float*)d_in[3];
  const float* bk = (const float*)d_in[4];
  const float* Wv = (const float*)d_in[5];
  const float* bv = (const float*)d_in[6];
  const float* Wo = (const float*)d_in[7];
  const float* bo = (const float*)d_in[8];
  const float* temp = (const float*)d_in[9];
  const void* mask = (const void*)d_in[10];

  char* ws = (char*)d_ws;
  u16* xb = (u16*)(ws + 256);                 // 8 MiB (x bf16; reused as oh later)
  u16* Wt = xb + (size_t)4 * 1024 * 1024;     // 8 MiB (Wq^T,Wk^T,Wv^T,Wo^T bf16)
  u16* qbuf = Wt + (size_t)4 * 1024 * 1024;   // 8 MiB [B,H,S,D] (q pre-scaled)
  u16* kbuf = qbuf + (size_t)4 * 1024 * 1024; // 8 MiB [B,H,S,D]
  u16* vTb = kbuf + (size_t)4 * 1024 * 1024;  // 8 MiB [B,H,D,S]
  u64* mbits = (u64*)(vTb + (size_t)4 * 1024 * 1024);  // 8 MiB bitmask
  u16* oh = xb;                               // alias: xb dead after QKV GEMM

  maskbits_kernel<<<4096, 256, 0, stream>>>(mask, mbits);
  xcvt_kernel<<<4096, 256, 0, stream>>>(x, xb);
  wcvt_kernel<<<dim3(32, 32, 4), 256, 0, stream>>>(Wq, Wk, Wv, Wo, Wt);
  gemm128_kernel<<<dim3(32, 8, 3), 256, 0, stream>>>(
      xb, Wt, Wt + 1024 * 1024, Wt + 2 * 1024 * 1024,
      bq, bk, bv, temp, qbuf, kbuf, vTb, nullptr, 0);
  attn_kernel<<<512, 256, 0, stream>>>(qbuf, kbuf, vTb, mbits, oh);
  gemm128_kernel<<<dim3(32, 8, 1), 256, 0, stream>>>(
      oh, Wt + 3 * 1024 * 1024, nullptr, nullptr,
      bo, nullptr, nullptr, temp, nullptr, nullptr, nullptr, (float*)d_out, 1);
}

// Round 5
// 192.097 us; speedup vs baseline: 1.7194x; 1.0054x over previous
//
#include <hip/hip_runtime.h>

typedef unsigned short u16;
typedef short short8 __attribute__((ext_vector_type(8)));
typedef float f32x4 __attribute__((ext_vector_type(4)));
typedef float float4v __attribute__((ext_vector_type(4)));
typedef u16 u16x4 __attribute__((ext_vector_type(4)));
typedef unsigned long long u64;

// ---------- helpers ----------
__device__ __forceinline__ u16 f2bf(float f) {
  union { float f; unsigned u; } v; v.f = f;
  unsigned r = v.u + 0x7FFFu + ((v.u >> 16) & 1u);   // round-to-nearest-even
  return (u16)(r >> 16);
}

__device__ __forceinline__ unsigned cvtpk(float lo, float hi) {
  unsigned r;
  asm("v_cvt_pk_bf16_f32 %0, %1, %2" : "=v"(r) : "v"(lo), "v"(hi));
  return r;
}

__device__ __forceinline__ void gload16(const u16* g, u16* l) {
  __builtin_amdgcn_global_load_lds(
      (const __attribute__((address_space(1))) void*)g,
      (__attribute__((address_space(3))) void*)l, 16, 0, 0);
}

// ---------- merged prep: maskbits (blocks 0..4095), xcvt (4096..8191), wcvt (8192..12287) ----------
__global__ __launch_bounds__(256)
void prep_kernel(const void* __restrict__ mask, u64* __restrict__ bits,
                 const float* __restrict__ x, u16* __restrict__ xb,
                 const float* __restrict__ W0, const float* __restrict__ W1,
                 const float* __restrict__ W2, const float* __restrict__ W3,
                 u16* __restrict__ Wt) {
  __shared__ float t[32][33];
  __shared__ int sf;
  const int bid = blockIdx.x;
  if (bid < 4096) {
    // ---- maskbits with self-detected dtype (fmt: 0=u8, 1=i32, 2=f32, 3=i64) ----
    if (threadIdx.x == 0) sf = 0;
    __syncthreads();
    {
      uint4 v = ((const uint4*)mask)[threadIdx.x];
      unsigned xs[4] = {v.x, v.y, v.z, v.w};
      int f = 0;
#pragma unroll
      for (int d = 0; d < 4; ++d) {
        unsigned u = xs[d];
        if (u == 0x3F800000u) f |= 1;   // f32 1.0
        if (u & 0xFFFFFF00u) f |= 2;    // nonzero byte off dword base -> u8
        if ((d & 1) && u) f |= 4;       // nonzero odd dword -> i32
      }
      if (f) atomicOr(&sf, f);
    }
    __syncthreads();
    const int fl = sf;
    const int fmt = (fl & 1) ? 2 : ((fl & 2) ? 0 : ((fl & 4) ? 1 : 3));

    const int wi = bid * 256 + threadIdx.x;  // 1M words
    u64 b = 0;
    if (fmt == 0) {
      const uint4* mp = (const uint4*)mask + (size_t)wi * 4;
#pragma unroll
      for (int i = 0; i < 4; ++i) {
        uint4 v = mp[i];
        unsigned xw[4] = {v.x, v.y, v.z, v.w};
#pragma unroll
        for (int d = 0; d < 4; ++d)
#pragma unroll
          for (int by = 0; by < 4; ++by)
            if (xw[d] & (0xFFu << (by * 8))) b |= 1ULL << (i * 16 + d * 4 + by);
      }
    } else if (fmt != 3) {  // 4-byte elements
      const uint4* mp = (const uint4*)mask + (size_t)wi * 16;
#pragma unroll
      for (int i = 0; i < 16; ++i) {
        uint4 v = mp[i];
        if (v.x) b |= 1ULL << (i * 4 + 0);
        if (v.y) b |= 1ULL << (i * 4 + 1);
        if (v.z) b |= 1ULL << (i * 4 + 2);
        if (v.w) b |= 1ULL << (i * 4 + 3);
      }
    } else {  // i64
      const uint4* mp = (const uint4*)mask + (size_t)wi * 32;
#pragma unroll
      for (int i = 0; i < 32; ++i) {
        uint4 v = mp[i];
        if (v.x | v.y) b |= 1ULL << (i * 2 + 0);
        if (v.z | v.w) b |= 1ULL << (i * 2 + 1);
      }
    }
    int bh = wi >> 14, q = (wi >> 4) & 1023, kt = wi & 15;
    bits[((size_t)bh * 16 + kt) * 1024 + q] = b;
  } else if (bid < 8192) {
    // ---- xcvt ----
    int i = ((bid - 4096) * 256 + threadIdx.x) * 4;
    float4v v = *(const float4v*)(x + i);
    u16x4 o;
    o[0] = f2bf(v[0]); o[1] = f2bf(v[1]); o[2] = f2bf(v[2]); o[3] = f2bf(v[3]);
    *(u16x4*)(xb + i) = o;
  } else {
    // ---- wcvt: f32 [K][N] -> bf16 [N][K] ----
    int i = bid - 8192;
    int z = i >> 10, rest = i & 1023;
    const float* W = (z == 0) ? W0 : (z == 1) ? W1 : (z == 2) ? W2 : W3;
    u16* out = Wt + (size_t)z * 1024 * 1024;
    int n0 = (rest & 31) * 32, k0 = (rest >> 5) * 32;
    int tx = threadIdx.x & 31, ty = threadIdx.x >> 5;
#pragma unroll
    for (int j = 0; j < 4; ++j)
      t[ty + 8 * j][tx] = W[(size_t)(k0 + ty + 8 * j) * 1024 + n0 + tx];
    __syncthreads();
#pragma unroll
    for (int j = 0; j < 4; ++j)
      out[(size_t)(n0 + ty + 8 * j) * 1024 + k0 + tx] = f2bf(t[tx][ty + 8 * j]);
  }
}

// ---------- 128xBN bf16 GEMM, A[M][K] x Bt[N][K]^T + bias ----------
// phase 0 (BN=128): z=0 -> q (pre-scaled by temp/sqrt(D)*log2e), z=1 -> k,
//                   z=2 -> vT via swapped-operand MFMA (acc holds C^T, coalesced store)
// phase 1: f32 output
template<int BN>
__global__ __launch_bounds__(256)
void gemm_kernel(const u16* __restrict__ A,
                 const u16* __restrict__ Bt0, const u16* __restrict__ Bt1, const u16* __restrict__ Bt2,
                 const float* __restrict__ b0, const float* __restrict__ b1, const float* __restrict__ b2,
                 const float* __restrict__ temp,
                 u16* __restrict__ qb, u16* __restrict__ kb, u16* __restrict__ vT,
                 float* __restrict__ fo, int phase) {
  constexpr int K = 1024;
  constexpr int WN = BN / 2;
  constexpr int NC = WN / 16;
  __shared__ u16 As[128 * 32];
  __shared__ u16 Bs[BN * 32];
  const int tid = threadIdx.x;
  const int lane = tid & 63, w = tid >> 6;
  const int l15 = lane & 15, l4 = lane >> 4;
  const int m0 = blockIdx.x * 128, n0 = blockIdx.y * BN;
  const int z = blockIdx.z;
  const u16* Bt = (z == 0) ? Bt0 : (z == 1) ? Bt1 : Bt2;
  const float* bias = (z == 0) ? b0 : (z == 1) ? b1 : b2;
  const int wr = w >> 1, wc = w & 1;
  const bool ct = (phase == 0) && (z == 2);

  f32x4 acc[4][NC] = {};

  const int c0 = tid, c1 = 256 + tid;
  const u16* ga0 = A + (size_t)(m0 + (c0 >> 2)) * K + (c0 & 3) * 8;
  const u16* ga1 = A + (size_t)(m0 + (c1 >> 2)) * K + (c1 & 3) * 8;
  const u16* gb0 = Bt + (size_t)(n0 + (c0 >> 2)) * K + (c0 & 3) * 8;
  const u16* gb1 = Bt + (size_t)(n0 + (c1 >> 2)) * K + (c1 & 3) * 8;
  u16* la0 = As + c0 * 8;
  u16* la1 = As + c1 * 8;
  u16* lb0 = Bs + c0 * 8;
  u16* lb1 = Bs + c1 * 8;

  for (int kt = 0; kt < K; kt += 32) {
    gload16(ga0 + kt, la0);
    gload16(ga1 + kt, la1);
    gload16(gb0 + kt, lb0);
    if (BN == 128) gload16(gb1 + kt, lb1);
    __syncthreads();
    short8 af[4], bfr[NC];
#pragma unroll
    for (int r = 0; r < 4; ++r)
      af[r] = *(const short8*)(As + (wr * 64 + r * 16 + l15) * 32 + l4 * 8);
#pragma unroll
    for (int c = 0; c < NC; ++c)
      bfr[c] = *(const short8*)(Bs + (wc * WN + c * 16 + l15) * 32 + l4 * 8);
    if (ct) {
#pragma unroll
      for (int r = 0; r < 4; ++r)
#pragma unroll
        for (int c = 0; c < NC; ++c)
          acc[r][c] = __builtin_amdgcn_mfma_f32_16x16x32_bf16(bfr[c], af[r], acc[r][c], 0, 0, 0);
    } else {
#pragma unroll
      for (int r = 0; r < 4; ++r)
#pragma unroll
        for (int c = 0; c < NC; ++c)
          acc[r][c] = __builtin_amdgcn_mfma_f32_16x16x32_bf16(af[r], bfr[c], acc[r][c], 0, 0, 0);
    }
    __syncthreads();
  }

  if (ct) {
    // acc = C^T: row = n-local (c*16 + l4*4 + j), col = m-local (r*16 + l15)
    float bvj[NC][4];
#pragma unroll
    for (int c = 0; c < NC; ++c)
#pragma unroll
      for (int j = 0; j < 4; ++j)
        bvj[c][j] = bias[n0 + wc * WN + c * 16 + l4 * 4 + j];
#pragma unroll
    for (int r = 0; r < 4; ++r) {
#pragma unroll
      for (int c = 0; c < NC; ++c) {
#pragma unroll
        for (int j = 0; j < 4; ++j) {
          float val = acc[r][c][j] + bvj[c][j];
          int n = n0 + wc * WN + c * 16 + l4 * 4 + j;   // h*64+d
          int mm = m0 + wr * 64 + r * 16 + l15;          // b*1024+s (lane-contig)
          int b = mm >> 10, s = mm & 1023;
          vT[((size_t)b * 1024 + n) * 1024 + s] = f2bf(val);
        }
      }
    }
  } else {
    float bv4[NC], fac4[NC];
#pragma unroll
    for (int c = 0; c < NC; ++c) {
      int col = n0 + wc * WN + c * 16 + l15;
      bv4[c] = bias[col];
      fac4[c] = (phase == 0 && z == 0) ? temp[col >> 6] * 0.18033688011112042f : 1.0f;
    }
#pragma unroll
    for (int r = 0; r < 4; ++r) {
#pragma unroll
      for (int c = 0; c < NC; ++c) {
#pragma unroll
        for (int j = 0; j < 4; ++j) {
          float val = (acc[r][c][j] + bv4[c]) * fac4[c];
          int row = m0 + wr * 64 + r * 16 + l4 * 4 + j;  // b*1024+s
          int col = n0 + wc * WN + c * 16 + l15;         // h*64+d
          if (phase == 0) {
            int b = row >> 10, s = row & 1023, hh = col >> 6, d = col & 63;
            u16* dst = (z == 0) ? qb : kb;
            dst[(((size_t)b * 16 + hh) * 1024 + s) * 64 + d] = f2bf(val);
          } else {
            fo[(size_t)row * 1024 + col] = val;
          }
        }
      }
    }
  }
}

// ---------- per-q-group masked online softmax + P write (scores pre-scaled) ----------
__device__ __forceinline__ void softmax_pwrite(const f32x4* s, u64 wcur,
                                               float& m, float& l, f32x4* oacc,
                                               char* Prow, int swzP, int l4) {
  float xx[4][4];
#pragma unroll
  for (int cb = 0; cb < 4; ++cb) {
    unsigned nib = (unsigned)(wcur >> (cb * 16 + l4 * 4)) & 15u;
#pragma unroll
    for (int j = 0; j < 4; ++j)
      xx[cb][j] = ((nib >> j) & 1) ? s[cb][j] : -1e30f;
  }
  float mt = xx[0][0];
#pragma unroll
  for (int cb = 0; cb < 4; ++cb)
#pragma unroll
    for (int j = 0; j < 4; ++j) mt = fmaxf(mt, xx[cb][j]);
  mt = fmaxf(mt, __shfl_xor(mt, 16));
  mt = fmaxf(mt, __shfl_xor(mt, 32));
  if (!__all(mt <= m + 8.f)) {   // T13 defer-max; fully-masked tiles self-heal via al=0 later
    float mnew = fmaxf(m, mt);
    float al = exp2f(m - mnew);
    l *= al;
#pragma unroll
    for (int db = 0; db < 4; ++db) oacc[db] *= al;
    m = mnew;
  }
  float rs = 0.f;
#pragma unroll
  for (int cb = 0; cb < 4; ++cb)
#pragma unroll
    for (int j = 0; j < 4; ++j) {
      xx[cb][j] = exp2f(xx[cb][j] - m);
      rs += xx[cb][j];
    }
  rs += __shfl_xor(rs, 16);
  rs += __shfl_xor(rs, 32);
  l += rs;
#pragma unroll
  for (int cb = 0; cb < 4; ++cb) {
    unsigned w0 = cvtpk(xx[cb][0], xx[cb][1]);
    unsigned w1 = cvtpk(xx[cb][2], xx[cb][3]);
    unsigned o2[2] = {w0, w1};
    *(unsigned long long*)(Prow + ((cb * 32 + l4 * 8) ^ swzP)) = *(unsigned long long*)o2;
  }
}

// ---------- flash attention: KBLK=128 (2 subtiles per barrier), QBLK=32/wave ----------
__global__ __launch_bounds__(256)
void attn_kernel(const u16* __restrict__ qb, const u16* __restrict__ kb, const u16* __restrict__ vT,
                 const u64* __restrict__ mbits, u16* __restrict__ oh) {
  __shared__ u16 Ks[2][128 * 64];  // 32 KiB: [k][d]
  __shared__ u16 Vs[2][64 * 128];  // 32 KiB: [d][k]
  __shared__ u16 P[4][32 * 64];    // 16 KiB per-wave P
  const int tid = threadIdx.x, lane = tid & 63, w = tid >> 6;
  const int l15 = lane & 15, l4 = lane >> 4;
  const int id = blockIdx.x;           // 512 blocks: 8 xcd x 8 bh x 8 qx
  const int xcd = id & 7, sl = id >> 3;
  const int bh = xcd * 8 + (sl >> 3), qx = sl & 7;
  const int b = bh >> 4, h = bh & 15;
  const int q0 = qx * 128 + w * 32;
  const u16* qp = qb + ((size_t)bh * 1024 + q0) * 64;
  const u16* kp = kb + (size_t)bh * 1024 * 64;
  const u16* vp = vT + (size_t)bh * 64 * 1024;
  char* Pw = (char*)&P[w][0];
  const int swzP = (l15 & 7) << 4;
  char* ProwA = Pw + l15 * 128;
  char* ProwB = Pw + (16 + l15) * 128;
  const int swzK = (l15 & 7) << 3;   // u16-index XOR (byte bits 4-6 / col bits 3-5)

  // staging chunks: 4 K-chunks + 4 V-chunks per thread per buffer (16B each)
  int krow[4], kcol[4], vrow[4], vcol[4];
#pragma unroll
  for (int i = 0; i < 4; ++i) {
    int c = tid + 256 * i;
    krow[i] = c >> 3; kcol[i] = ((c & 7) ^ (krow[i] & 7)) * 8;
    vrow[i] = c >> 4; vcol[i] = ((c & 15) ^ (vrow[i] & 7)) * 8;
  }

  // Q fragments (pre-scaled)
  short8 qa0 = *(const short8*)(qp + (size_t)l15 * 64 + l4 * 8);
  short8 qa1 = *(const short8*)(qp + (size_t)l15 * 64 + 32 + l4 * 8);
  short8 qb0 = *(const short8*)(qp + (size_t)(16 + l15) * 64 + l4 * 8);
  short8 qb1 = *(const short8*)(qp + (size_t)(16 + l15) * 64 + 32 + l4 * 8);

  float ma = -1e30f, la = 0.f, mbv = -1e30f, lb = 0.f;
  f32x4 oa[4] = {}, ob[4] = {};

  const u64* mba = mbits + (size_t)bh * 16 * 1024 + q0 + l15;
  u64 wa[2], wb[2];
  wa[0] = mba[0]; wa[1] = mba[1024];
  wb[0] = mba[16]; wb[1] = mba[1024 + 16];

  // prologue: stage k-tile 0
#pragma unroll
  for (int i = 0; i < 4; ++i) {
    gload16(kp + (size_t)krow[i] * 64 + kcol[i], &Ks[0][(tid + 256 * i) * 8]);
    gload16(vp + (size_t)vrow[i] * 1024 + vcol[i], &Vs[0][(tid + 256 * i) * 8]);
  }

  for (int t = 0; t < 8; ++t) {
    const int buf = t & 1;
    __syncthreads();  // stage(t) drained (vmcnt(0) before barrier)

    if (t < 7) {
      const int k1 = (t + 1) * 128;
#pragma unroll
      for (int i = 0; i < 4; ++i) {
        gload16(kp + (size_t)(k1 + krow[i]) * 64 + kcol[i], &Ks[buf ^ 1][(tid + 256 * i) * 8]);
        gload16(vp + (size_t)vrow[i] * 1024 + k1 + vcol[i], &Vs[buf ^ 1][(tid + 256 * i) * 8]);
      }
    }
    u64 nwa[2] = {0, 0}, nwb[2] = {0, 0};
    if (t < 7) {
      nwa[0] = mba[(2 * t + 2) * 1024];      nwa[1] = mba[(2 * t + 3) * 1024];
      nwb[0] = mba[(2 * t + 2) * 1024 + 16]; nwb[1] = mba[(2 * t + 3) * 1024 + 16];
    }

#pragma unroll
    for (int st = 0; st < 2; ++st) {
      // ---- S^T = K Q^T (both q-groups, K-frags reused) ----
      f32x4 sa[4] = {}, sb[4] = {};
      __builtin_amdgcn_s_setprio(1);
#pragma unroll
      for (int cb = 0; cb < 4; ++cb) {
        const u16* kr = &Ks[buf][(st * 64 + cb * 16 + l15) * 64];
        short8 kf0 = *(const short8*)(kr + ((l4 * 8) ^ swzK));
        short8 kf1 = *(const short8*)(kr + ((32 + l4 * 8) ^ swzK));
        sa[cb] = __builtin_amdgcn_mfma_f32_16x16x32_bf16(kf0, qa0, sa[cb], 0, 0, 0);
        sa[cb] = __builtin_amdgcn_mfma_f32_16x16x32_bf16(kf1, qa1, sa[cb], 0, 0, 0);
        sb[cb] = __builtin_amdgcn_mfma_f32_16x16x32_bf16(kf0, qb0, sb[cb], 0, 0, 0);
        sb[cb] = __builtin_amdgcn_mfma_f32_16x16x32_bf16(kf1, qb1, sb[cb], 0, 0, 0);
      }
      __builtin_amdgcn_s_setprio(0);

      softmax_pwrite(sa, wa[st], ma, la, oa, ProwA, swzP, l4);
      softmax_pwrite(sb, wb[st], mbv, lb, ob, ProwB, swzP, l4);

      // ---- O^T += V^T P^T (V-frags reused across q-groups) ----
      __builtin_amdgcn_s_setprio(1);
#pragma unroll
      for (int ks = 0; ks < 2; ++ks) {
        short8 pa = *(const short8*)(ProwA + ((ks * 64 + l4 * 16) ^ swzP));
        short8 pbf = *(const short8*)(ProwB + ((ks * 64 + l4 * 16) ^ swzP));
#pragma unroll
        for (int db = 0; db < 4; ++db) {
          short8 vf = *(const short8*)(&Vs[buf][(db * 16 + l15) * 128 +
                                                ((st * 64 + ks * 32 + l4 * 8) ^ swzK)]);
          oa[db] = __builtin_amdgcn_mfma_f32_16x16x32_bf16(vf, pa, oa[db], 0, 0, 0);
          ob[db] = __builtin_amdgcn_mfma_f32_16x16x32_bf16(vf, pbf, ob[db], 0, 0, 0);
        }
      }
      __builtin_amdgcn_s_setprio(0);
    }
    wa[0] = nwa[0]; wa[1] = nwa[1]; wb[0] = nwb[0]; wb[1] = nwb[1];
  }

  // ---- finalize ----
  float rla = 1.f / la, rlb = 1.f / lb;
  u16* orowA = oh + ((size_t)b * 1024 + q0 + l15) * 1024 + h * 64;
  u16* orowB = oh + ((size_t)b * 1024 + q0 + 16 + l15) * 1024 + h * 64;
#pragma unroll
  for (int db = 0; db < 4; ++db) {
    unsigned a0 = cvtpk(oa[db][0] * rla, oa[db][1] * rla);
    unsigned a1 = cvtpk(oa[db][2] * rla, oa[db][3] * rla);
    unsigned b0 = cvtpk(ob[db][0] * rlb, ob[db][1] * rlb);
    unsigned b1 = cvtpk(ob[db][2] * rlb, ob[db][3] * rlb);
    unsigned oA[2] = {a0, a1}, oB[2] = {b0, b1};
    *(unsigned long long*)(orowA + db * 16 + l4 * 4) = *(unsigned long long*)oA;
    *(unsigned long long*)(orowB + db * 16 + l4 * 4) = *(unsigned long long*)oB;
  }
}

// ---------- launch ----------
extern "C" void kernel_launch(void* const* d_in, const int* in_sizes, int n_in,
                              void* d_out, int out_size, void* d_ws, size_t ws_size,
                              hipStream_t stream) {
  const float* x = (const float*)d_in[0];
  const float* Wq = (const float*)d_in[1];
  const float* bq = (const float*)d_in[2];
  const float* Wk = (const float*)d_in[3];
  const float* bk = (const float*)d_in[4];
  const float* Wv = (const float*)d_in[5];
  const float* bv = (const float*)d_in[6];
  const float* Wo = (const float*)d_in[7];
  const float* bo = (const float*)d_in[8];
  const float* temp = (const float*)d_in[9];
  const void* mask = (const void*)d_in[10];

  char* ws = (char*)d_ws;
  u16* xb = (u16*)(ws + 256);                 // 8 MiB (x bf16; reused as oh later)
  u16* Wt = xb + (size_t)4 * 1024 * 1024;     // 8 MiB (Wq^T,Wk^T,Wv^T,Wo^T bf16)
  u16* qbuf = Wt + (size_t)4 * 1024 * 1024;   // 8 MiB [B,H,S,D] (q pre-scaled)
  u16* kbuf = qbuf + (size_t)4 * 1024 * 1024; // 8 MiB [B,H,S,D]
  u16* vTb = kbuf + (size_t)4 * 1024 * 1024;  // 8 MiB [B,H,D,S]
  u64* mbits = (u64*)(vTb + (size_t)4 * 1024 * 1024);  // 8 MiB bitmask
  u16* oh = xb;                               // alias: xb dead after QKV GEMM

  prep_kernel<<<12288, 256, 0, stream>>>(mask, mbits, x, xb, Wq, Wk, Wv, Wo, Wt);
  gemm_kernel<128><<<dim3(32, 8, 3), 256, 0, stream>>>(
      xb, Wt, Wt + 1024 * 1024, Wt + 2 * 1024 * 1024,
      bq, bk, bv, temp, qbuf, kbuf, vTb, nullptr, 0);
  attn_kernel<<<512, 256, 0, stream>>>(qbuf, kbuf, vTb, mbits, oh);
  gemm_kernel<64><<<dim3(32, 16, 1), 256, 0, stream>>>(
      oh, Wt + 3 * 1024 * 1024, nullptr, nullptr,
      bo, nullptr, nullptr, temp, nullptr, nullptr, nullptr, (float*)d_out, 1);
}